// Round 1
// baseline (335.748 us; speedup 1.0000x reference)
//
#include <hip/hip_runtime.h>
#include <hip/hip_bf16.h>

typedef float f32x4 __attribute__((ext_vector_type(4)));
typedef __bf16 bf16x8 __attribute__((ext_vector_type(8)));
typedef unsigned short us8 __attribute__((ext_vector_type(8)));
typedef unsigned short us4 __attribute__((ext_vector_type(4)));
typedef unsigned short us2 __attribute__((ext_vector_type(2)));

#define DEVI __device__ __forceinline__

DEVI unsigned short f2bf(float x) {
  return __builtin_bit_cast(unsigned short, __float2bfloat16(x));
}
DEVI float bf2f(unsigned short u) {
  return __builtin_bit_cast(float, ((unsigned int)u) << 16);
}
DEVI bf16x8 ldb8(const unsigned short* p) {
  return __builtin_bit_cast(bf16x8, *(const us8*)p);
}

// ---------------- fp32 -> bf16 convert ----------------
__global__ __launch_bounds__(256) void cvt_k(const float* __restrict__ in,
                                             unsigned short* __restrict__ out, int n) {
  int i = (blockIdx.x * 256 + threadIdx.x) * 4;
  if (i >= n) return;
  float4 v = *(const float4*)(in + i);
  us4 r = {f2bf(v.x), f2bf(v.y), f2bf(v.z), f2bf(v.w)};
  *(us4*)(out + i) = r;
}

// ---------------- GEMM: C[M,N] = A[M,K] @ W[N,K]^T + bias ----------------
// EPI: 0 = bf16 out, 1 = exact-GELU -> bf16 out, 2 = f32 out
template <int EPI>
__global__ __launch_bounds__(256) void gemm_bt(const unsigned short* __restrict__ A,
                                               const unsigned short* __restrict__ W,
                                               const float* __restrict__ bias,
                                               void* __restrict__ Cout,
                                               int M, int N, int K) {
  // 128x128 tile, BK=32, 4 waves in 2x2, each wave 64x64 (4x4 16x16 frags).
  // LDS stride 40 shorts (80B = 5*16B): keeps ds_read_b128 16B-aligned,
  // spreads row-parallel fragment reads across banks.
  __shared__ unsigned short As[128][40];
  __shared__ unsigned short Bs[128][40];
  const int t = threadIdx.x, l = t & 63, w = t >> 6;
  const int wr = w >> 1, wc = w & 1;
  const int l4 = l & 15, lg = l >> 4;
  const int brow = blockIdx.y * 128, bcol = blockIdx.x * 128;
  f32x4 acc[4][4] = {};
  for (int kt = 0; kt < K; kt += 32) {
    __syncthreads();
#pragma unroll
    for (int i = 0; i < 2; ++i) {
      int idx = i * 256 + t;          // 512 chunks of 16B each for A and B
      int row = idx >> 2, ks = idx & 3;
      *(us8*)(&As[row][ks * 8]) = *(const us8*)(A + (size_t)(brow + row) * K + kt + ks * 8);
      *(us8*)(&Bs[row][ks * 8]) = *(const us8*)(W + (size_t)(bcol + row) * K + kt + ks * 8);
    }
    __syncthreads();
    bf16x8 af[4], bfr[4];
#pragma unroll
    for (int mi = 0; mi < 4; ++mi) af[mi] = ldb8(&As[wr * 64 + mi * 16 + l4][lg * 8]);
#pragma unroll
    for (int ni = 0; ni < 4; ++ni) bfr[ni] = ldb8(&Bs[wc * 64 + ni * 16 + l4][lg * 8]);
#pragma unroll
    for (int mi = 0; mi < 4; ++mi)
#pragma unroll
      for (int ni = 0; ni < 4; ++ni)
        acc[mi][ni] = __builtin_amdgcn_mfma_f32_16x16x32_bf16(af[mi], bfr[ni], acc[mi][ni], 0, 0, 0);
  }
  // epilogue. C/D layout (m89-verified): col = lane&15, row = (lane>>4)*4 + reg
#pragma unroll
  for (int mi = 0; mi < 4; ++mi)
#pragma unroll
    for (int ni = 0; ni < 4; ++ni) {
      int row0 = brow + wr * 64 + mi * 16 + lg * 4;
      int col = bcol + wc * 64 + ni * 16 + l4;
      float bv = bias[col];
#pragma unroll
      for (int r = 0; r < 4; ++r) {
        float v = acc[mi][ni][r] + bv;
        if (EPI == 1) v = 0.5f * v * (1.0f + erff(v * 0.70710678118f));  // exact gelu
        if (EPI == 2)
          ((float*)Cout)[(size_t)(row0 + r) * N + col] = v;
        else
          ((unsigned short*)Cout)[(size_t)(row0 + r) * N + col] = f2bf(v);
      }
    }
}

// ---------------- VAD layer 2: out[row,3] = tanh(h1[row,:512] @ w2[3,512]^T + b2) ----------------
__global__ __launch_bounds__(256) void vad2_k(const unsigned short* __restrict__ h1,
                                              const float* __restrict__ w2,
                                              const float* __restrict__ b2,
                                              float* __restrict__ out) {
  const int t = threadIdx.x, l = t & 63, w = t >> 6;
  const int row = blockIdx.x * 4 + w;  // one wave per row
  us8 hv = *(const us8*)(h1 + (size_t)row * 512 + l * 8);
  float hf[8];
#pragma unroll
  for (int j = 0; j < 8; ++j) hf[j] = bf2f(hv[j]);
  float s[3];
#pragma unroll
  for (int c = 0; c < 3; ++c) {
    const float* wp = w2 + c * 512 + l * 8;
    float a = 0.f;
#pragma unroll
    for (int j = 0; j < 8; ++j) a += hf[j] * wp[j];
    s[c] = a;
  }
#pragma unroll
  for (int m = 1; m < 64; m <<= 1) {
#pragma unroll
    for (int c = 0; c < 3; ++c) s[c] += __shfl_xor(s[c], m, 64);
  }
  if (l == 0) {
#pragma unroll
    for (int c = 0; c < 3; ++c) out[(size_t)row * 3 + c] = tanhf(s[c] + b2[c]);
  }
}

// ---------------- flash attention with VAD affinity ----------------
// block = (q-tile 64 rows, head, batch); 4 waves, wave w owns score rows w*16..w*16+15
__global__ __launch_bounds__(256) void attn_k(const unsigned short* __restrict__ Qp,
                                              const unsigned short* __restrict__ Kp,
                                              const unsigned short* __restrict__ Vp,
                                              const float* __restrict__ vadq,
                                              const float* __restrict__ vadk,
                                              const float* __restrict__ plam,
                                              unsigned short* __restrict__ Obuf) {
  __shared__ unsigned short Qs[64][72];   // 144B rows, 16B aligned for b128
  __shared__ unsigned short Ks[64][72];
  __shared__ unsigned short Vs[64][66];   // 132B rows: strided u16 B-frag reads land 2/bank (free)
  __shared__ unsigned short Ps[4][16][72];
  __shared__ float vqs[192], vks[192];
  const int t = threadIdx.x, l = t & 63, w = t >> 6;
  const int l4 = l & 15, lg = l >> 4;
  const int qb = blockIdx.x, h = blockIdx.y, b = blockIdx.z;
  const float lam = plam[0];
  const size_t qrow0 = (size_t)b * 1024 + qb * 64;
  const int hoff = h * 64;

  // stage Q tile (once)
#pragma unroll
  for (int i = 0; i < 2; ++i) {
    int idx = i * 256 + t;
    int row = idx >> 3, sl = idx & 7;
    *(us8*)(&Qs[row][sl * 8]) = *(const us8*)(Qp + (qrow0 + row) * 1024 + hoff + sl * 8);
  }
  if (t < 192) vqs[t] = vadq[qrow0 * 3 + t];
  __syncthreads();

  bf16x8 qf[2];
#pragma unroll
  for (int ks = 0; ks < 2; ++ks) qf[ks] = ldb8(&Qs[w * 16 + l4][ks * 32 + lg * 8]);
  float vqr[4][3];
#pragma unroll
  for (int r = 0; r < 4; ++r) {
    int rr = w * 16 + lg * 4 + r;
#pragma unroll
    for (int c = 0; c < 3; ++c) vqr[r][c] = vqs[rr * 3 + c];
  }
  float m_run[4], l_run[4];
  f32x4 accO[4] = {};
#pragma unroll
  for (int r = 0; r < 4; ++r) { m_run[r] = -1e30f; l_run[r] = 0.f; }

  for (int kt = 0; kt < 16; ++kt) {
    __syncthreads();  // all waves done reading previous K/V
    const size_t krow0 = (size_t)b * 1024 + kt * 64;
#pragma unroll
    for (int i = 0; i < 2; ++i) {
      int idx = i * 256 + t;
      int row = idx >> 3, sl = idx & 7;
      *(us8*)(&Ks[row][sl * 8]) = *(const us8*)(Kp + (krow0 + row) * 1024 + hoff + sl * 8);
      us8 vvv = *(const us8*)(Vp + (krow0 + row) * 1024 + hoff + sl * 8);
#pragma unroll
      for (int k2 = 0; k2 < 4; ++k2) {   // 66-stride rows are only 4B aligned -> b32 writes
        us2 w2v = {vvv[k2 * 2], vvv[k2 * 2 + 1]};
        *(us2*)(&Vs[row][sl * 8 + k2 * 2]) = w2v;
      }
    }
    if (t < 192) vks[t] = vadk[krow0 * 3 + t];
    __syncthreads();

    // QK^T: scores[i][j] = sum_d Q[i][d] K[j][d]
    f32x4 sc[4] = {};
#pragma unroll
    for (int jt = 0; jt < 4; ++jt) {
#pragma unroll
      for (int ks = 0; ks < 2; ++ks) {
        bf16x8 kf = ldb8(&Ks[jt * 16 + l4][ks * 32 + lg * 8]);
        sc[jt] = __builtin_amdgcn_mfma_f32_16x16x32_bf16(qf[ks], kf, sc[jt], 0, 0, 0);
      }
    }
    // scale + VAD affinity + online softmax (per-row ops in 16-lane groups)
    float pv[4][4], vmax[4];
#pragma unroll
    for (int r = 0; r < 4; ++r) vmax[r] = -1e30f;
#pragma unroll
    for (int jt = 0; jt < 4; ++jt) {
      int j = jt * 16 + l4;
      float k0 = vks[j * 3], k1 = vks[j * 3 + 1], k2 = vks[j * 3 + 2];
#pragma unroll
      for (int r = 0; r < 4; ++r) {
        float dx = vqr[r][0] - k0, dy = vqr[r][1] - k1, dz = vqr[r][2] - k2;
        float s = sc[jt][r] * 0.125f - lam * sqrtf(dx * dx + dy * dy + dz * dz);
        pv[jt][r] = s;
        vmax[r] = fmaxf(vmax[r], s);
      }
    }
#pragma unroll
    for (int m = 1; m < 16; m <<= 1) {
#pragma unroll
      for (int r = 0; r < 4; ++r) vmax[r] = fmaxf(vmax[r], __shfl_xor(vmax[r], m, 64));
    }
    float fs[4], rs[4];
#pragma unroll
    for (int r = 0; r < 4; ++r) {
      float mn = fmaxf(m_run[r], vmax[r]);
      fs[r] = __expf(m_run[r] - mn);
      m_run[r] = mn;
      rs[r] = 0.f;
#pragma unroll
      for (int jt = 0; jt < 4; ++jt) { pv[jt][r] = __expf(pv[jt][r] - mn); rs[r] += pv[jt][r]; }
    }
#pragma unroll
    for (int m = 1; m < 16; m <<= 1) {
#pragma unroll
      for (int r = 0; r < 4; ++r) rs[r] += __shfl_xor(rs[r], m, 64);
    }
#pragma unroll
    for (int r = 0; r < 4; ++r) l_run[r] = l_run[r] * fs[r] + rs[r];
#pragma unroll
    for (int dt = 0; dt < 4; ++dt)
#pragma unroll
      for (int r = 0; r < 4; ++r) accO[dt][r] = accO[dt][r] * fs[r];
    // transpose P through per-wave LDS (C-layout -> A-fragment layout)
#pragma unroll
    for (int jt = 0; jt < 4; ++jt)
#pragma unroll
      for (int r = 0; r < 4; ++r)
        Ps[w][lg * 4 + r][jt * 16 + l4] = f2bf(pv[jt][r]);
    // PV: out[i][d] += P[i][j] V[j][d]   (same-wave LDS dep; compiler inserts lgkmcnt)
#pragma unroll
    for (int js = 0; js < 2; ++js) {
      bf16x8 pa = ldb8(&Ps[w][l4][js * 32 + lg * 8]);
#pragma unroll
      for (int dt = 0; dt < 4; ++dt) {
        us8 vv;
#pragma unroll
        for (int jj = 0; jj < 8; ++jj) vv[jj] = Vs[js * 32 + lg * 8 + jj][dt * 16 + l4];
        accO[dt] = __builtin_amdgcn_mfma_f32_16x16x32_bf16(pa, __builtin_bit_cast(bf16x8, vv),
                                                           accO[dt], 0, 0, 0);
      }
    }
  }
  // epilogue: normalize and store bf16
#pragma unroll
  for (int r = 0; r < 4; ++r) l_run[r] = 1.f / l_run[r];
#pragma unroll
  for (int dt = 0; dt < 4; ++dt)
#pragma unroll
    for (int r = 0; r < 4; ++r) {
      float v = accO[dt][r] * l_run[r];
      Obuf[(qrow0 + w * 16 + lg * 4 + r) * 1024 + hoff + dt * 16 + l4] = f2bf(v);
    }
}

// ---------------- residual + layernorm ----------------
__global__ __launch_bounds__(256) void ln_k(const float* __restrict__ q,
                                            const float* __restrict__ tin,
                                            const float* __restrict__ g,
                                            const float* __restrict__ bb,
                                            float* __restrict__ out) {
  __shared__ float red[8];
  const int row = blockIdx.x, t = threadIdx.x;
  const int l = t & 63, w = t >> 6;
  const size_t base = (size_t)row * 1024 + t * 4;
  float4 a = *(const float4*)(q + base);
  float4 c = *(const float4*)(tin + base);
  float x0 = a.x + c.x, x1 = a.y + c.y, x2 = a.z + c.z, x3 = a.w + c.w;
  float s = x0 + x1 + x2 + x3;
#pragma unroll
  for (int m = 1; m < 64; m <<= 1) s += __shfl_xor(s, m, 64);
  if (l == 0) red[w] = s;
  __syncthreads();
  float mean = (red[0] + red[1] + red[2] + red[3]) * (1.f / 1024.f);
  float d0 = x0 - mean, d1 = x1 - mean, d2 = x2 - mean, d3 = x3 - mean;
  float v = d0 * d0 + d1 * d1 + d2 * d2 + d3 * d3;
#pragma unroll
  for (int m = 1; m < 64; m <<= 1) v += __shfl_xor(v, m, 64);
  if (l == 0) red[4 + w] = v;
  __syncthreads();
  float var = (red[4] + red[5] + red[6] + red[7]) * (1.f / 1024.f);
  float rstd = rsqrtf(var + 1e-5f);
  float4 gv = *(const float4*)(g + t * 4);
  float4 bv = *(const float4*)(bb + t * 4);
  float4 o;
  o.x = d0 * rstd * gv.x + bv.x;
  o.y = d1 * rstd * gv.y + bv.y;
  o.z = d2 * rstd * gv.z + bv.z;
  o.w = d3 * rstd * gv.w + bv.w;
  *(float4*)(out + (size_t)row * 1024 + t * 4) = o;
}

extern "C" void kernel_launch(void* const* d_in, const int* in_sizes, int n_in,
                              void* d_out, int out_size, void* d_ws, size_t ws_size,
                              hipStream_t stream) {
  const float* query = (const float*)d_in[0];
  const float* key_  = (const float*)d_in[1];
  const float* value = (const float*)d_in[2];
  const float* wq = (const float*)d_in[3];
  const float* bq = (const float*)d_in[4];
  const float* wk = (const float*)d_in[5];
  const float* bk = (const float*)d_in[6];
  const float* wv = (const float*)d_in[7];
  const float* bv = (const float*)d_in[8];
  const float* wo = (const float*)d_in[9];
  const float* bo = (const float*)d_in[10];
  const float* w1 = (const float*)d_in[11];
  const float* b1 = (const float*)d_in[12];
  const float* w2 = (const float*)d_in[13];
  const float* b2 = (const float*)d_in[14];
  const float* lam = (const float*)d_in[15];
  const float* lng = (const float*)d_in[16];
  const float* lnb = (const float*)d_in[17];

  char* ws = (char*)d_ws;
  size_t off = 0;
  auto alloc = [&](size_t n) { char* p = ws + off; off += (n + 255) & ~(size_t)255; return p; };
  unsigned short* qb  = (unsigned short*)alloc(8388608);   // query bf16 [4096,1024]
  unsigned short* kb  = (unsigned short*)alloc(8388608);
  unsigned short* vb  = (unsigned short*)alloc(8388608);
  unsigned short* wqb = (unsigned short*)alloc(2097152);
  unsigned short* wkb = (unsigned short*)alloc(2097152);
  unsigned short* wvb = (unsigned short*)alloc(2097152);
  unsigned short* wob = (unsigned short*)alloc(2097152);
  unsigned short* w1b = (unsigned short*)alloc(1048576);
  unsigned short* Qp  = (unsigned short*)alloc(8388608);   // projected Q bf16
  unsigned short* Kp  = (unsigned short*)alloc(8388608);
  unsigned short* Vp  = (unsigned short*)alloc(8388608);
  unsigned short* h1q = (unsigned short*)alloc(4194304);   // gelu(x@w1^T) bf16 [4096,512]
  unsigned short* h1k = (unsigned short*)alloc(4194304);
  float* vadq = (float*)alloc(49152);                      // [4096,3]
  float* vadk = (float*)alloc(49152);
  unsigned short* Obuf = (unsigned short*)alloc(8388608);  // attention out bf16
  float* tmp = (float*)alloc(16777216);                    // Wo out fp32

  cvt_k<<<4096, 256, 0, stream>>>(query, qb, 4194304);
  cvt_k<<<4096, 256, 0, stream>>>(key_, kb, 4194304);
  cvt_k<<<4096, 256, 0, stream>>>(value, vb, 4194304);
  cvt_k<<<1024, 256, 0, stream>>>(wq, wqb, 1048576);
  cvt_k<<<1024, 256, 0, stream>>>(wk, wkb, 1048576);
  cvt_k<<<1024, 256, 0, stream>>>(wv, wvb, 1048576);
  cvt_k<<<1024, 256, 0, stream>>>(wo, wob, 1048576);
  cvt_k<<<512, 256, 0, stream>>>(w1, w1b, 524288);

  dim3 g1024(8, 32), g512(4, 32);
  gemm_bt<0><<<g1024, 256, 0, stream>>>(qb, wqb, bq, Qp, 4096, 1024, 1024);
  gemm_bt<0><<<g1024, 256, 0, stream>>>(kb, wkb, bk, Kp, 4096, 1024, 1024);
  gemm_bt<0><<<g1024, 256, 0, stream>>>(vb, wvb, bv, Vp, 4096, 1024, 1024);
  gemm_bt<1><<<g512, 256, 0, stream>>>(qb, w1b, b1, h1q, 4096, 512, 1024);
  gemm_bt<1><<<g512, 256, 0, stream>>>(kb, w1b, b1, h1k, 4096, 512, 1024);
  vad2_k<<<1024, 256, 0, stream>>>(h1q, w2, b2, vadq);
  vad2_k<<<1024, 256, 0, stream>>>(h1k, w2, b2, vadk);
  attn_k<<<dim3(16, 16, 4), 256, 0, stream>>>(Qp, Kp, Vp, vadq, vadk, lam, Obuf);
  gemm_bt<2><<<g1024, 256, 0, stream>>>(Obuf, wob, bo, tmp, 4096, 1024, 1024);
  ln_k<<<4096, 256, 0, stream>>>(query, tmp, lng, lnb, (float*)d_out);
}

// Round 2
// 236.834 us; speedup vs baseline: 1.4177x; 1.4177x over previous
//
#include <hip/hip_runtime.h>
#include <hip/hip_bf16.h>

typedef float f32x4 __attribute__((ext_vector_type(4)));
typedef __bf16 bf16x8 __attribute__((ext_vector_type(8)));
typedef unsigned short us8 __attribute__((ext_vector_type(8)));

#define DEVI __device__ __forceinline__

DEVI unsigned short f2bf(float x) {
  return __builtin_bit_cast(unsigned short, __float2bfloat16(x));
}
DEVI float bf2f(unsigned short u) {
  return __builtin_bit_cast(float, ((unsigned int)u) << 16);
}
DEVI bf16x8 ldb8(const unsigned short* p) {
  return __builtin_bit_cast(bf16x8, *(const us8*)p);
}
DEVI void gload16(const unsigned short* g, unsigned short* l) {
  __builtin_amdgcn_global_load_lds(
      (const __attribute__((address_space(1))) unsigned int*)(const void*)g,
      (__attribute__((address_space(3))) unsigned int*)(void*)l, 16, 0, 0);
}

// ---------------- fp32 -> bf16 convert, 4-way batched via grid.y ----------------
__global__ __launch_bounds__(256) void cvt_k(const float* __restrict__ p0, const float* __restrict__ p1,
                                             const float* __restrict__ p2, const float* __restrict__ p3,
                                             unsigned short* __restrict__ o0, unsigned short* __restrict__ o1,
                                             unsigned short* __restrict__ o2, unsigned short* __restrict__ o3,
                                             int n) {
  const float* in;
  unsigned short* out;
  switch (blockIdx.y) {
    case 0: in = p0; out = o0; break;
    case 1: in = p1; out = o1; break;
    case 2: in = p2; out = o2; break;
    default: in = p3; out = o3; break;
  }
  int i = (blockIdx.x * 256 + threadIdx.x) * 8;
  if (i >= n) return;
  float4 a = *(const float4*)(in + i);
  float4 b = *(const float4*)(in + i + 4);
  us8 r = {f2bf(a.x), f2bf(a.y), f2bf(a.z), f2bf(a.w), f2bf(b.x), f2bf(b.y), f2bf(b.z), f2bf(b.w)};
  *(us8*)(out + i) = r;
}

// ---------------- GEMM (m97 structure): C = A[M,K] @ W[N,K]^T + bias ----------------
// EPI: 0 = bf16 out col-bias; 1 = GELU bf16 out col-bias; 2 = f32 out col-bias; 3 = bf16 out ROW-bias
// 2-way batched via grid.z. oscale multiplies (acc+bias).
template <int EPI>
__global__ __launch_bounds__(256) void gemm_k(const unsigned short* __restrict__ A0, const unsigned short* __restrict__ A1,
                                              const unsigned short* __restrict__ W0, const unsigned short* __restrict__ W1,
                                              const float* __restrict__ bias0, const float* __restrict__ bias1,
                                              void* __restrict__ C0, void* __restrict__ C1,
                                              int M, int N, int K, float os0, float os1) {
  const unsigned short* A = blockIdx.z ? A1 : A0;
  const unsigned short* W = blockIdx.z ? W1 : W0;
  const float* bias = blockIdx.z ? bias1 : bias0;
  void* Cout = blockIdx.z ? (void*)C1 : (void*)C0;
  const float oscale = blockIdx.z ? os1 : os0;
  __shared__ unsigned short As[128 * 32];
  __shared__ unsigned short Bs[128 * 32];
  const int t = threadIdx.x, l = t & 63;
  const int w4 = t >> 6, wr = w4 >> 1, wc = w4 & 1;
  const int l4 = l & 15, lg = l >> 4;
  const int brow = blockIdx.y * 128, bcol = blockIdx.x * 128;
  const int r0 = t >> 2, q0 = (t & 3) * 8, r1 = r0 + 64;  // chunk->row/elem (4 chunks of 8 elems per 32-col row)
  f32x4 acc[4][4] = {};
  for (int kt = 0; kt < K; kt += 32) {
    __syncthreads();
    gload16(A + (size_t)(brow + r0) * K + kt + q0, As + t * 8);
    gload16(A + (size_t)(brow + r1) * K + kt + q0, As + (t + 256) * 8);
    gload16(W + (size_t)(bcol + r0) * K + kt + q0, Bs + t * 8);
    gload16(W + (size_t)(bcol + r1) * K + kt + q0, Bs + (t + 256) * 8);
    __syncthreads();
    bf16x8 af[4], bfr[4];
#pragma unroll
    for (int mi = 0; mi < 4; ++mi) af[mi] = ldb8(&As[(wr * 64 + mi * 16 + l4) * 32 + lg * 8]);
#pragma unroll
    for (int ni = 0; ni < 4; ++ni) bfr[ni] = ldb8(&Bs[(wc * 64 + ni * 16 + l4) * 32 + lg * 8]);
#pragma unroll
    for (int mi = 0; mi < 4; ++mi)
#pragma unroll
      for (int ni = 0; ni < 4; ++ni)
        acc[mi][ni] = __builtin_amdgcn_mfma_f32_16x16x32_bf16(af[mi], bfr[ni], acc[mi][ni], 0, 0, 0);
  }
#pragma unroll
  for (int mi = 0; mi < 4; ++mi)
#pragma unroll
    for (int ni = 0; ni < 4; ++ni) {
      int row0 = brow + wr * 64 + mi * 16 + lg * 4;
      int col = bcol + wc * 64 + ni * 16 + l4;
#pragma unroll
      for (int r = 0; r < 4; ++r) {
        float v;
        if (EPI == 3)
          v = (acc[mi][ni][r] + bias[row0 + r]) * oscale;
        else
          v = (acc[mi][ni][r] + bias[col]) * oscale;
        if (EPI == 1) v = 0.5f * v * (1.0f + erff(v * 0.70710678118f));
        if (EPI == 2)
          ((float*)Cout)[(size_t)(row0 + r) * N + col] = v;
        else
          ((unsigned short*)Cout)[(size_t)(row0 + r) * N + col] = f2bf(v);
      }
    }
}

// ---------------- VAD layer 2 (batched grid.y): out[row,3] = tanh(h1 @ w2^T + b2) ----------------
__global__ __launch_bounds__(256) void vad2_k(const unsigned short* __restrict__ h1a, const unsigned short* __restrict__ h1b,
                                              const float* __restrict__ w2, const float* __restrict__ b2,
                                              float* __restrict__ outa, float* __restrict__ outb) {
  const unsigned short* h1 = blockIdx.y ? h1b : h1a;
  float* out = blockIdx.y ? outb : outa;
  const int t = threadIdx.x, l = t & 63, w = t >> 6;
  const int row = blockIdx.x * 4 + w;
  us8 hv = *(const us8*)(h1 + (size_t)row * 512 + l * 8);
  float hf[8];
#pragma unroll
  for (int j = 0; j < 8; ++j) hf[j] = bf2f(hv[j]);
  float s[3];
#pragma unroll
  for (int c = 0; c < 3; ++c) {
    const float* wp = w2 + c * 512 + l * 8;
    float a = 0.f;
#pragma unroll
    for (int j = 0; j < 8; ++j) a += hf[j] * wp[j];
    s[c] = a;
  }
#pragma unroll
  for (int m = 1; m < 64; m <<= 1) {
#pragma unroll
    for (int c = 0; c < 3; ++c) s[c] += __shfl_xor(s[c], m, 64);
  }
  if (l == 0) {
#pragma unroll
    for (int c = 0; c < 3; ++c) out[(size_t)row * 3 + c] = tanhf(s[c] + b2[c]);
  }
}

// ---------------- affinity precompute: aff[b][q][k] = -lam * ||vq-vk|| (bf16) ----------------
__global__ __launch_bounds__(256) void aff_k(const float* __restrict__ vq, const float* __restrict__ vk,
                                             const float* __restrict__ plam, unsigned short* __restrict__ aff) {
  __shared__ float vqs[64][3], vks[64][3];
  const int t = threadIdx.x;
  const int b = blockIdx.z, q0 = blockIdx.y * 64, k0 = blockIdx.x * 64;
  const float lam = plam[0];
  if (t < 192) ((float*)vqs)[t] = vq[((size_t)b * 1024 + q0) * 3 + t];
  if (t >= 64 && t < 256) ((float*)vks)[t - 64] = vk[((size_t)b * 1024 + k0) * 3 + (t - 64)];
  __syncthreads();
  const int q = t >> 2, kc = (t & 3) * 16;
  const float a0 = vqs[q][0], a1 = vqs[q][1], a2 = vqs[q][2];
  unsigned short o[16];
#pragma unroll
  for (int j = 0; j < 16; ++j) {
    int k = kc + j;
    float dx = a0 - vks[k][0], dy = a1 - vks[k][1], dz = a2 - vks[k][2];
    o[j] = f2bf(-lam * sqrtf(dx * dx + dy * dy + dz * dz));
  }
  unsigned short* dst = aff + ((size_t)(b * 1024 + q0 + q)) * 1024 + k0 + kc;
  *(us8*)dst = *(us8*)&o[0];
  *(us8*)(dst + 8) = *(us8*)&o[8];
}

// ---------------- flash attention (Q pre-scaled; V pre-transposed; aff precomputed) ----------------
__global__ __launch_bounds__(256, 4) void attn_k(const unsigned short* __restrict__ Qp,
                                                 const unsigned short* __restrict__ Kp,
                                                 const unsigned short* __restrict__ Vt,
                                                 const unsigned short* __restrict__ aff,
                                                 unsigned short* __restrict__ Obuf) {
  __shared__ unsigned short Qs[64 * 64];   // linear [row][64], both-sides XOR swizzle (chunk ^= row&7)
  __shared__ unsigned short Ks[64 * 64];
  __shared__ unsigned short Vs[64 * 64];   // logical [d][k], same swizzle
  __shared__ unsigned short Ps[4][16][72];
  const int t = threadIdx.x, l = t & 63, w = t >> 6;
  const int l4 = l & 15, lg = l >> 4;
  const int qb = blockIdx.x, h = blockIdx.y, b = blockIdx.z;
  const size_t qrow0 = (size_t)b * 1024 + qb * 64;
  const int hoff = h * 64;
  // stage Q (swizzled global source -> linear LDS dest)
  {
    int c0 = t, r0 = c0 >> 3, s0 = (c0 & 7) ^ (r0 & 7);
    gload16(Qp + (qrow0 + r0) * 1024 + hoff + s0 * 8, Qs + c0 * 8);
    int c1 = t + 256, r1 = c1 >> 3, s1 = (c1 & 7) ^ (r1 & 7);
    gload16(Qp + (qrow0 + r1) * 1024 + hoff + s1 * 8, Qs + c1 * 8);
  }
  __syncthreads();
  bf16x8 qf[2];
#pragma unroll
  for (int ks = 0; ks < 2; ++ks)
    qf[ks] = ldb8(&Qs[(w * 16 + l4) * 64 + (((ks * 4 + lg) ^ (l4 & 7))) * 8]);
  float m_run[4], l_run[4];
  f32x4 accO[4] = {};
#pragma unroll
  for (int r = 0; r < 4; ++r) { m_run[r] = -1e30f; l_run[r] = 0.f; }
  const unsigned short* ab = aff + (qrow0 + w * 16 + lg * 4) * 1024 + l4;

  for (int kt = 0; kt < 16; ++kt) {
    __syncthreads();  // all waves done reading previous K/V
    {
      const unsigned short* gk = Kp + ((size_t)b * 1024 + kt * 64) * 1024 + hoff;
      const unsigned short* gv = Vt + (size_t)hoff * 4096 + (size_t)b * 1024 + kt * 64;
      int c0 = t, r0 = c0 >> 3, s0 = (c0 & 7) ^ (r0 & 7);
      gload16(gk + (size_t)r0 * 1024 + s0 * 8, Ks + c0 * 8);
      gload16(gv + (size_t)r0 * 4096 + s0 * 8, Vs + c0 * 8);
      int c1 = t + 256, r1 = c1 >> 3, s1 = (c1 & 7) ^ (r1 & 7);
      gload16(gk + (size_t)r1 * 1024 + s1 * 8, Ks + c1 * 8);
      gload16(gv + (size_t)r1 * 4096 + s1 * 8, Vs + c1 * 8);
    }
    // affinity loads (bf16, L2-resident; 16 scalar loads w/ immediate offsets)
    float aval[4][4];
#pragma unroll
    for (int jt = 0; jt < 4; ++jt)
#pragma unroll
      for (int r = 0; r < 4; ++r) aval[jt][r] = bf2f(ab[kt * 64 + r * 1024 + jt * 16]);
    __syncthreads();
    // QK^T (Q pre-scaled by 0.125)
    f32x4 sc[4] = {};
#pragma unroll
    for (int jt = 0; jt < 4; ++jt) {
#pragma unroll
      for (int ks = 0; ks < 2; ++ks) {
        bf16x8 kf = ldb8(&Ks[(jt * 16 + l4) * 64 + (((ks * 4 + lg) ^ (l4 & 7))) * 8]);
        sc[jt] = __builtin_amdgcn_mfma_f32_16x16x32_bf16(qf[ks], kf, sc[jt], 0, 0, 0);
      }
    }
    // guided scores + online softmax (rows spread over 16-lane groups)
    float pv[4][4], vmax[4];
#pragma unroll
    for (int r = 0; r < 4; ++r) vmax[r] = -1e30f;
#pragma unroll
    for (int jt = 0; jt < 4; ++jt)
#pragma unroll
      for (int r = 0; r < 4; ++r) {
        float s = sc[jt][r] + aval[jt][r];
        pv[jt][r] = s;
        vmax[r] = fmaxf(vmax[r], s);
      }
#pragma unroll
    for (int m = 1; m < 16; m <<= 1) {
#pragma unroll
      for (int r = 0; r < 4; ++r) vmax[r] = fmaxf(vmax[r], __shfl_xor(vmax[r], m, 64));
    }
    float fs[4], rs[4];
#pragma unroll
    for (int r = 0; r < 4; ++r) {
      float mn = fmaxf(m_run[r], vmax[r]);
      fs[r] = __expf(m_run[r] - mn);
      m_run[r] = mn;
      rs[r] = 0.f;
#pragma unroll
      for (int jt = 0; jt < 4; ++jt) { pv[jt][r] = __expf(pv[jt][r] - mn); rs[r] += pv[jt][r]; }
    }
#pragma unroll
    for (int m = 1; m < 16; m <<= 1) {
#pragma unroll
      for (int r = 0; r < 4; ++r) rs[r] += __shfl_xor(rs[r], m, 64);
    }
#pragma unroll
    for (int r = 0; r < 4; ++r) l_run[r] = l_run[r] * fs[r] + rs[r];
#pragma unroll
    for (int dt = 0; dt < 4; ++dt)
#pragma unroll
      for (int r = 0; r < 4; ++r) accO[dt][r] = accO[dt][r] * fs[r];
    // transpose P through per-wave LDS (C-layout -> A-fragment layout)
#pragma unroll
    for (int jt = 0; jt < 4; ++jt)
#pragma unroll
      for (int r = 0; r < 4; ++r)
        Ps[w][lg * 4 + r][jt * 16 + l4] = f2bf(pv[jt][r]);
    // PV: A-frag = P rows, B-frag = one b128 from transposed V
#pragma unroll
    for (int js = 0; js < 2; ++js) {
      bf16x8 pa = ldb8(&Ps[w][l4][js * 32 + lg * 8]);
#pragma unroll
      for (int dt = 0; dt < 4; ++dt) {
        bf16x8 vf = ldb8(&Vs[(dt * 16 + l4) * 64 + (((js * 4 + lg) ^ (l4 & 7))) * 8]);
        accO[dt] = __builtin_amdgcn_mfma_f32_16x16x32_bf16(pa, vf, accO[dt], 0, 0, 0);
      }
    }
  }
#pragma unroll
  for (int r = 0; r < 4; ++r) l_run[r] = 1.f / l_run[r];
#pragma unroll
  for (int dt = 0; dt < 4; ++dt)
#pragma unroll
    for (int r = 0; r < 4; ++r) {
      float v = accO[dt][r] * l_run[r];
      Obuf[(qrow0 + w * 16 + lg * 4 + r) * 1024 + hoff + dt * 16 + l4] = f2bf(v);
    }
}

// ---------------- residual + layernorm ----------------
__global__ __launch_bounds__(256) void ln_k(const float* __restrict__ q,
                                            const float* __restrict__ tin,
                                            const float* __restrict__ g,
                                            const float* __restrict__ bb,
                                            float* __restrict__ out) {
  __shared__ float red[8];
  const int row = blockIdx.x, t = threadIdx.x;
  const int l = t & 63, w = t >> 6;
  const size_t base = (size_t)row * 1024 + t * 4;
  float4 a = *(const float4*)(q + base);
  float4 c = *(const float4*)(tin + base);
  float x0 = a.x + c.x, x1 = a.y + c.y, x2 = a.z + c.z, x3 = a.w + c.w;
  float s = x0 + x1 + x2 + x3;
#pragma unroll
  for (int m = 1; m < 64; m <<= 1) s += __shfl_xor(s, m, 64);
  if (l == 0) red[w] = s;
  __syncthreads();
  float mean = (red[0] + red[1] + red[2] + red[3]) * (1.f / 1024.f);
  float d0 = x0 - mean, d1 = x1 - mean, d2 = x2 - mean, d3 = x3 - mean;
  float v = d0 * d0 + d1 * d1 + d2 * d2 + d3 * d3;
#pragma unroll
  for (int m = 1; m < 64; m <<= 1) v += __shfl_xor(v, m, 64);
  if (l == 0) red[4 + w] = v;
  __syncthreads();
  float var = (red[4] + red[5] + red[6] + red[7]) * (1.f / 1024.f);
  float rstd = rsqrtf(var + 1e-5f);
  float4 gv = *(const float4*)(g + t * 4);
  float4 bv = *(const float4*)(bb + t * 4);
  float4 o;
  o.x = d0 * rstd * gv.x + bv.x;
  o.y = d1 * rstd * gv.y + bv.y;
  o.z = d2 * rstd * gv.z + bv.z;
  o.w = d3 * rstd * gv.w + bv.w;
  *(float4*)(out + (size_t)row * 1024 + t * 4) = o;
}

extern "C" void kernel_launch(void* const* d_in, const int* in_sizes, int n_in,
                              void* d_out, int out_size, void* d_ws, size_t ws_size,
                              hipStream_t stream) {
  const float* query = (const float*)d_in[0];
  const float* key_  = (const float*)d_in[1];
  const float* value = (const float*)d_in[2];
  const float* wq = (const float*)d_in[3];
  const float* bq = (const float*)d_in[4];
  const float* wk = (const float*)d_in[5];
  const float* bk = (const float*)d_in[6];
  const float* wv = (const float*)d_in[7];
  const float* bv = (const float*)d_in[8];
  const float* wo = (const float*)d_in[9];
  const float* bo = (const float*)d_in[10];
  const float* w1 = (const float*)d_in[11];
  const float* b1 = (const float*)d_in[12];
  const float* w2 = (const float*)d_in[13];
  const float* b2 = (const float*)d_in[14];
  const float* lam = (const float*)d_in[15];
  const float* lng = (const float*)d_in[16];
  const float* lnb = (const float*)d_in[17];

  char* ws = (char*)d_ws;
  size_t off = 0;
  auto alloc = [&](size_t n) { char* p = ws + off; off += (n + 255) & ~(size_t)255; return p; };
  unsigned short* qb  = (unsigned short*)alloc(8388608);   // query bf16 [4096,1024]
  unsigned short* kb  = (unsigned short*)alloc(8388608);
  unsigned short* vb  = (unsigned short*)alloc(8388608);
  unsigned short* wqb = (unsigned short*)alloc(2097152);
  unsigned short* wkb = (unsigned short*)alloc(2097152);
  unsigned short* wvb = (unsigned short*)alloc(2097152);
  unsigned short* wob = (unsigned short*)alloc(2097152);
  unsigned short* w1b = (unsigned short*)alloc(1048576);
  unsigned short* Qp  = (unsigned short*)alloc(8388608);   // projected Q (pre-scaled by 0.125) bf16
  unsigned short* Kp  = (unsigned short*)alloc(8388608);
  unsigned short* Vt  = (unsigned short*)alloc(8388608);   // V^T bf16 [1024 d_model][4096 tokens]
  unsigned short* h1q = (unsigned short*)alloc(4194304);   // gelu(x@w1^T) bf16 [4096,512]
  unsigned short* h1k = (unsigned short*)alloc(4194304);
  float* vadq = (float*)alloc(49152);                      // [4096,3]
  float* vadk = (float*)alloc(49152);
  unsigned short* Obuf = (unsigned short*)alloc(8388608);  // attention out bf16
  // aliases (stream-ordered lifetimes): aff over vb (dead after gemmV); tmp over qb+kb (dead after gemmH1)
  unsigned short* aff = vb;                                // [4,1024,1024] bf16
  float* tmp = (float*)qb;                                 // Wo out fp32 [4096,1024]

  cvt_k<<<dim3(2048, 3), 256, 0, stream>>>(query, key_, value, value, qb, kb, vb, vb, 4194304);
  cvt_k<<<dim3(512, 4), 256, 0, stream>>>(wq, wk, wv, wo, wqb, wkb, wvb, wob, 1048576);
  cvt_k<<<dim3(256, 1), 256, 0, stream>>>(w1, w1, w1, w1, w1b, w1b, w1b, w1b, 524288);

  // Q/K projections batched; Q pre-scaled by SCALE=0.125
  gemm_k<0><<<dim3(8, 32, 2), 256, 0, stream>>>(qb, kb, wqb, wkb, bq, bk, Qp, Kp,
                                                4096, 1024, 1024, 0.125f, 1.f);
  // V^T directly: C'[d_model][token] = Wv @ X^T (row-bias)
  gemm_k<3><<<dim3(32, 8, 1), 256, 0, stream>>>(wvb, wvb, vb, vb, bv, bv, Vt, Vt,
                                                1024, 4096, 1024, 1.f, 1.f);
  // VAD layer 1 (GELU) batched for query/key
  gemm_k<1><<<dim3(4, 32, 2), 256, 0, stream>>>(qb, kb, w1b, w1b, b1, b1, h1q, h1k,
                                                4096, 512, 1024, 1.f, 1.f);
  vad2_k<<<dim3(1024, 2), 256, 0, stream>>>(h1q, h1k, w2, b2, vadq, vadk);
  aff_k<<<dim3(16, 16, 4), 256, 0, stream>>>(vadq, vadk, lam, aff);
  attn_k<<<dim3(16, 16, 4), 256, 0, stream>>>(Qp, Kp, Vt, aff, Obuf);
  gemm_k<2><<<dim3(8, 32, 1), 256, 0, stream>>>(Obuf, Obuf, wob, wob, bo, bo, tmp, tmp,
                                                4096, 1024, 1024, 1.f, 1.f);
  ln_k<<<4096, 256, 0, stream>>>(query, tmp, lng, lnb, (float*)d_out);
}

// Round 3
// 220.317 us; speedup vs baseline: 1.5239x; 1.0750x over previous
//
#include <hip/hip_runtime.h>
#include <hip/hip_bf16.h>

typedef float f32x4 __attribute__((ext_vector_type(4)));
typedef __bf16 bf16x8 __attribute__((ext_vector_type(8)));
typedef unsigned short us8 __attribute__((ext_vector_type(8)));
typedef unsigned short us4 __attribute__((ext_vector_type(4)));

#define DEVI __device__ __forceinline__
#define LOG2E 1.44269504088896f

DEVI unsigned short f2bf(float x) {
  return __builtin_bit_cast(unsigned short, __float2bfloat16(x));
}
DEVI float bf2f(unsigned short u) {
  return __builtin_bit_cast(float, ((unsigned int)u) << 16);
}
DEVI bf16x8 ldb8(const unsigned short* p) {
  return __builtin_bit_cast(bf16x8, *(const us8*)p);
}
DEVI void gload16(const unsigned short* g, unsigned short* l) {
  __builtin_amdgcn_global_load_lds(
      (const __attribute__((address_space(1))) unsigned int*)(const void*)g,
      (__attribute__((address_space(3))) unsigned int*)(void*)l, 16, 0, 0);
}

// ---------------- fp32 -> bf16 convert, 4-way batched via grid.y ----------------
__global__ __launch_bounds__(256) void cvt_k(const float* __restrict__ p0, const float* __restrict__ p1,
                                             const float* __restrict__ p2, const float* __restrict__ p3,
                                             unsigned short* __restrict__ o0, unsigned short* __restrict__ o1,
                                             unsigned short* __restrict__ o2, unsigned short* __restrict__ o3,
                                             int n) {
  const float* in;
  unsigned short* out;
  switch (blockIdx.y) {
    case 0: in = p0; out = o0; break;
    case 1: in = p1; out = o1; break;
    case 2: in = p2; out = o2; break;
    default: in = p3; out = o3; break;
  }
  int i = (blockIdx.x * 256 + threadIdx.x) * 8;
  if (i >= n) return;
  float4 a = *(const float4*)(in + i);
  float4 b = *(const float4*)(in + i + 4);
  us8 r = {f2bf(a.x), f2bf(a.y), f2bf(a.z), f2bf(a.w), f2bf(b.x), f2bf(b.y), f2bf(b.z), f2bf(b.w)};
  *(us8*)(out + i) = r;
}

// ---------------- GEMM (m97 structure, BK=64, XOR-swizzled LDS): C = A @ W^T + bias ----------------
// EPI: 0 = bf16 col-bias; 1 = GELU bf16 col-bias; 2 = f32 col-bias; 3 = bf16 ROW-bias
template <int EPI>
__global__ __launch_bounds__(256) void gemm_k(const unsigned short* __restrict__ A0, const unsigned short* __restrict__ A1,
                                              const unsigned short* __restrict__ W0, const unsigned short* __restrict__ W1,
                                              const float* __restrict__ bias0, const float* __restrict__ bias1,
                                              void* __restrict__ C0, void* __restrict__ C1,
                                              int M, int N, int K, float os0, float os1) {
  const unsigned short* A = blockIdx.z ? A1 : A0;
  const unsigned short* W = blockIdx.z ? W1 : W0;
  const float* bias = blockIdx.z ? bias1 : bias0;
  void* Cout = blockIdx.z ? (void*)C1 : (void*)C0;
  const float oscale = blockIdx.z ? os1 : os0;
  __shared__ unsigned short As[8192];  // [128][64] bf16, chunk ^= row&7 swizzle
  __shared__ unsigned short Bs[8192];
  // T1: XCD-aware block swizzle (nwg multiple of 8 in all our launches)
  const int nx = gridDim.x;
  const int lin = blockIdx.y * nx + blockIdx.x;
  const int cpx = (nx * gridDim.y) >> 3;
  const int nl = (lin & 7) * cpx + (lin >> 3);
  const int bx = nl % nx, by = nl / nx;
  const int t = threadIdx.x, l = t & 63;
  const int w4 = t >> 6, wr = w4 >> 1, wc = w4 & 1;
  const int l4 = l & 15, lg = l >> 4;
  const int brow = by * 128, bcol = bx * 128;
  f32x4 acc[4][4] = {};
  for (int kt = 0; kt < K; kt += 64) {
    __syncthreads();
#pragma unroll
    for (int i = 0; i < 4; ++i) {
      int c = t + i * 256;                     // 1024 chunks of 16B per operand
      int row = c >> 3, sw = ((c & 7) ^ (row & 7)) * 8;
      gload16(A + (size_t)(brow + row) * K + kt + sw, As + c * 8);
      gload16(W + (size_t)(bcol + row) * K + kt + sw, Bs + c * 8);
    }
    __syncthreads();
#pragma unroll
    for (int ks = 0; ks < 2; ++ks) {
      bf16x8 af[4], bfr[4];
#pragma unroll
      for (int mi = 0; mi < 4; ++mi)
        af[mi] = ldb8(&As[(wr * 64 + mi * 16 + l4) * 64 + (((ks * 4 + lg) ^ (l4 & 7))) * 8]);
#pragma unroll
      for (int ni = 0; ni < 4; ++ni)
        bfr[ni] = ldb8(&Bs[(wc * 64 + ni * 16 + l4) * 64 + (((ks * 4 + lg) ^ (l4 & 7))) * 8]);
#pragma unroll
      for (int mi = 0; mi < 4; ++mi)
#pragma unroll
        for (int ni = 0; ni < 4; ++ni)
          acc[mi][ni] = __builtin_amdgcn_mfma_f32_16x16x32_bf16(af[mi], bfr[ni], acc[mi][ni], 0, 0, 0);
    }
  }
#pragma unroll
  for (int mi = 0; mi < 4; ++mi)
#pragma unroll
    for (int ni = 0; ni < 4; ++ni) {
      int row0 = brow + wr * 64 + mi * 16 + lg * 4;
      int col = bcol + wc * 64 + ni * 16 + l4;
#pragma unroll
      for (int r = 0; r < 4; ++r) {
        float v;
        if (EPI == 3)
          v = (acc[mi][ni][r] + bias[row0 + r]) * oscale;
        else
          v = (acc[mi][ni][r] + bias[col]) * oscale;
        if (EPI == 1) v = 0.5f * v * (1.0f + erff(v * 0.70710678118f));
        if (EPI == 2)
          ((float*)Cout)[(size_t)(row0 + r) * N + col] = v;
        else
          ((unsigned short*)Cout)[(size_t)(row0 + r) * N + col] = f2bf(v);
      }
    }
}

// ---------------- VAD layer 2 (batched grid.y) ----------------
__global__ __launch_bounds__(256) void vad2_k(const unsigned short* __restrict__ h1a, const unsigned short* __restrict__ h1b,
                                              const float* __restrict__ w2, const float* __restrict__ b2,
                                              float* __restrict__ outa, float* __restrict__ outb) {
  const unsigned short* h1 = blockIdx.y ? h1b : h1a;
  float* out = blockIdx.y ? outb : outa;
  const int t = threadIdx.x, l = t & 63, w = t >> 6;
  const int row = blockIdx.x * 4 + w;
  us8 hv = *(const us8*)(h1 + (size_t)row * 512 + l * 8);
  float hf[8];
#pragma unroll
  for (int j = 0; j < 8; ++j) hf[j] = bf2f(hv[j]);
  float s[3];
#pragma unroll
  for (int c = 0; c < 3; ++c) {
    const float* wp = w2 + c * 512 + l * 8;
    float a = 0.f;
#pragma unroll
    for (int j = 0; j < 8; ++j) a += hf[j] * wp[j];
    s[c] = a;
  }
#pragma unroll
  for (int m = 1; m < 64; m <<= 1) {
#pragma unroll
    for (int c = 0; c < 3; ++c) s[c] += __shfl_xor(s[c], m, 64);
  }
  if (l == 0) {
#pragma unroll
    for (int c = 0; c < 3; ++c) out[(size_t)row * 3 + c] = tanhf(s[c] + b2[c]);
  }
}

// ---------------- affinity precompute, TRANSPOSED + log2e-scaled: aff[b][k][q] ----------------
__global__ __launch_bounds__(256) void aff_k(const float* __restrict__ vq, const float* __restrict__ vk,
                                             const float* __restrict__ plam, unsigned short* __restrict__ aff) {
  __shared__ float vqs[64][3], vks[64][3];
  const int t = threadIdx.x;
  const int b = blockIdx.z, q0 = blockIdx.y * 64, k0 = blockIdx.x * 64;
  const float lam2 = plam[0] * LOG2E;
  if (t < 192) {
    ((float*)vqs)[t] = vq[((size_t)b * 1024 + q0) * 3 + t];
    ((float*)vks)[t] = vk[((size_t)b * 1024 + k0) * 3 + t];
  }
  __syncthreads();
  const int k = t >> 2, qc = (t & 3) * 16;
  const float k0f = vks[k][0], k1f = vks[k][1], k2f = vks[k][2];
  unsigned short o[16];
#pragma unroll
  for (int j = 0; j < 16; ++j) {
    int q = qc + j;
    float dx = vqs[q][0] - k0f, dy = vqs[q][1] - k1f, dz = vqs[q][2] - k2f;
    o[j] = f2bf(-lam2 * sqrtf(dx * dx + dy * dy + dz * dz));
  }
  unsigned short* dst = aff + ((size_t)(b * 1024 + k0 + k)) * 1024 + q0 + qc;
  *(us8*)dst = *(us8*)&o[0];
  *(us8*)(dst + 8) = *(us8*)&o[8];
}

// ---------------- flash attention: 2-phase dbuf pipeline, exp2 softmax, setprio, XCD swizzle ----------------
__global__ __launch_bounds__(256, 3) void attn_k(const unsigned short* __restrict__ Qp,
                                                 const unsigned short* __restrict__ Kp,
                                                 const unsigned short* __restrict__ Vt,
                                                 const unsigned short* __restrict__ aff,
                                                 unsigned short* __restrict__ Obuf) {
  __shared__ unsigned short Ks[2][4096];  // [64][64] bf16, chunk ^= row&7
  __shared__ unsigned short Vs[2][4096];  // logical [d][token]
  __shared__ unsigned short Qs[4096];
  __shared__ unsigned short Ps[4][16][72];
  // XCD swizzle: 16 q-blocks of one (h,b) stay on one XCD (shared K/V panel in L2)
  const int lin = blockIdx.x + 16 * (blockIdx.y + 16 * blockIdx.z);  // 1024 blocks
  const int nl = (lin & 7) * 128 + (lin >> 3);
  const int qb = nl & 15, h = (nl >> 4) & 15, b = nl >> 8;
  const int t = threadIdx.x, l = t & 63, w = t >> 6;
  const int l4 = l & 15, lg = l >> 4;
  const size_t qrow0 = (size_t)b * 1024 + qb * 64;
  const int hoff = h * 64;

  // prologue: stage Q and K/V tile 0
  {
    const unsigned short* gk = Kp + ((size_t)b * 1024) * 1024 + hoff;
    const unsigned short* gv = Vt + (size_t)hoff * 4096 + (size_t)b * 1024;
#pragma unroll
    for (int i = 0; i < 2; ++i) {
      int c = t + i * 256;
      int row = c >> 3, sw = ((c & 7) ^ (row & 7)) * 8;
      gload16(Qp + (qrow0 + row) * 1024 + hoff + sw, Qs + c * 8);
      gload16(gk + (size_t)row * 1024 + sw, Ks[0] + c * 8);
      gload16(gv + (size_t)row * 4096 + sw, Vs[0] + c * 8);
    }
  }
  __syncthreads();
  bf16x8 qf[2];
#pragma unroll
  for (int ks = 0; ks < 2; ++ks)
    qf[ks] = ldb8(&Qs[(w * 16 + l4) * 64 + (((ks * 4 + lg) ^ (l4 & 7))) * 8]);
  float m_run[4], l_run[4];
  f32x4 accO[4] = {};
#pragma unroll
  for (int r = 0; r < 4; ++r) { m_run[r] = -1e30f; l_run[r] = 0.f; }
  // transposed aff base: aff[(b*1024 + k)*1024 + q], us4 over r
  const unsigned short* ab = aff + ((size_t)b * 1024 + l4) * 1024 + qb * 64 + w * 16 + lg * 4;

  int cur = 0;
  for (int kt = 0; kt < 16; ++kt) {
    // issue next-tile stage FIRST: latency hides under this tile's compute
    if (kt < 15) {
      const unsigned short* gk = Kp + ((size_t)b * 1024 + (kt + 1) * 64) * 1024 + hoff;
      const unsigned short* gv = Vt + (size_t)hoff * 4096 + (size_t)b * 1024 + (kt + 1) * 64;
#pragma unroll
      for (int i = 0; i < 2; ++i) {
        int c = t + i * 256;
        int row = c >> 3, sw = ((c & 7) ^ (row & 7)) * 8;
        gload16(gk + (size_t)row * 1024 + sw, Ks[cur ^ 1] + c * 8);
        gload16(gv + (size_t)row * 4096 + sw, Vs[cur ^ 1] + c * 8);
      }
    }
    // affinity (bf16, transposed layout -> one us4 per jt)
    float aval[4][4];
#pragma unroll
    for (int jt = 0; jt < 4; ++jt) {
      us4 av = *(const us4*)(ab + (size_t)(kt * 64 + jt * 16) * 1024);
#pragma unroll
      for (int r = 0; r < 4; ++r) aval[jt][r] = bf2f(av[r]);
    }
    // QK^T (Q pre-scaled by SCALE*log2e)
    f32x4 sc[4] = {};
    __builtin_amdgcn_s_setprio(1);
#pragma unroll
    for (int jt = 0; jt < 4; ++jt) {
#pragma unroll
      for (int ks = 0; ks < 2; ++ks) {
        bf16x8 kf = ldb8(&Ks[cur][(jt * 16 + l4) * 64 + (((ks * 4 + lg) ^ (l4 & 7))) * 8]);
        sc[jt] = __builtin_amdgcn_mfma_f32_16x16x32_bf16(qf[ks], kf, sc[jt], 0, 0, 0);
      }
    }
    __builtin_amdgcn_s_setprio(0);
    // guided scores + online softmax in exp2 domain
    float pv[4][4], vmax[4];
#pragma unroll
    for (int r = 0; r < 4; ++r) vmax[r] = -1e30f;
#pragma unroll
    for (int jt = 0; jt < 4; ++jt)
#pragma unroll
      for (int r = 0; r < 4; ++r) {
        float s = sc[jt][r] + aval[jt][r];
        pv[jt][r] = s;
        vmax[r] = fmaxf(vmax[r], s);
      }
#pragma unroll
    for (int m = 1; m < 16; m <<= 1) {
#pragma unroll
      for (int r = 0; r < 4; ++r) vmax[r] = fmaxf(vmax[r], __shfl_xor(vmax[r], m, 64));
    }
    float fs[4], rs[4];
#pragma unroll
    for (int r = 0; r < 4; ++r) {
      float mn = fmaxf(m_run[r], vmax[r]);
      fs[r] = exp2f(m_run[r] - mn);
      m_run[r] = mn;
      rs[r] = 0.f;
#pragma unroll
      for (int jt = 0; jt < 4; ++jt) { pv[jt][r] = exp2f(pv[jt][r] - mn); rs[r] += pv[jt][r]; }
    }
#pragma unroll
    for (int m = 1; m < 16; m <<= 1) {
#pragma unroll
      for (int r = 0; r < 4; ++r) rs[r] += __shfl_xor(rs[r], m, 64);
    }
#pragma unroll
    for (int r = 0; r < 4; ++r) l_run[r] = l_run[r] * fs[r] + rs[r];
#pragma unroll
    for (int dt = 0; dt < 4; ++dt)
#pragma unroll
      for (int r = 0; r < 4; ++r) accO[dt][r] = accO[dt][r] * fs[r];
    // transpose P through per-wave LDS (C-layout -> A-fragment layout)
#pragma unroll
    for (int jt = 0; jt < 4; ++jt)
#pragma unroll
      for (int r = 0; r < 4; ++r)
        Ps[w][lg * 4 + r][jt * 16 + l4] = f2bf(pv[jt][r]);
    // PV from transposed V
    __builtin_amdgcn_s_setprio(1);
#pragma unroll
    for (int js = 0; js < 2; ++js) {
      bf16x8 pa = ldb8(&Ps[w][l4][js * 32 + lg * 8]);
#pragma unroll
      for (int dt = 0; dt < 4; ++dt) {
        bf16x8 vf = ldb8(&Vs[cur][(dt * 16 + l4) * 64 + (((js * 4 + lg) ^ (l4 & 7))) * 8]);
        accO[dt] = __builtin_amdgcn_mfma_f32_16x16x32_bf16(pa, vf, accO[dt], 0, 0, 0);
      }
    }
    __builtin_amdgcn_s_setprio(0);
    __syncthreads();  // single barrier per tile: drains next-tile stage, frees buf for overwrite
    cur ^= 1;
  }
#pragma unroll
  for (int r = 0; r < 4; ++r) l_run[r] = 1.f / l_run[r];
#pragma unroll
  for (int dt = 0; dt < 4; ++dt)
#pragma unroll
    for (int r = 0; r < 4; ++r) {
      float v = accO[dt][r] * l_run[r];
      Obuf[(qrow0 + w * 16 + lg * 4 + r) * 1024 + hoff + dt * 16 + l4] = f2bf(v);
    }
}

// ---------------- residual + layernorm ----------------
__global__ __launch_bounds__(256) void ln_k(const float* __restrict__ q,
                                            const float* __restrict__ tin,
                                            const float* __restrict__ g,
                                            const float* __restrict__ bb,
                                            float* __restrict__ out) {
  __shared__ float red[8];
  const int row = blockIdx.x, t = threadIdx.x;
  const int l = t & 63, w = t >> 6;
  const size_t base = (size_t)row * 1024 + t * 4;
  float4 a = *(const float4*)(q + base);
  float4 c = *(const float4*)(tin + base);
  float x0 = a.x + c.x, x1 = a.y + c.y, x2 = a.z + c.z, x3 = a.w + c.w;
  float s = x0 + x1 + x2 + x3;
#pragma unroll
  for (int m = 1; m < 64; m <<= 1) s += __shfl_xor(s, m, 64);
  if (l == 0) red[w] = s;
  __syncthreads();
  float mean = (red[0] + red[1] + red[2] + red[3]) * (1.f / 1024.f);
  float d0 = x0 - mean, d1 = x1 - mean, d2 = x2 - mean, d3 = x3 - mean;
  float v = d0 * d0 + d1 * d1 + d2 * d2 + d3 * d3;
#pragma unroll
  for (int m = 1; m < 64; m <<= 1) v += __shfl_xor(v, m, 64);
  if (l == 0) red[4 + w] = v;
  __syncthreads();
  float var = (red[4] + red[5] + red[6] + red[7]) * (1.f / 1024.f);
  float rstd = rsqrtf(var + 1e-5f);
  float4 gv = *(const float4*)(g + t * 4);
  float4 bv = *(const float4*)(bb + t * 4);
  float4 o;
  o.x = d0 * rstd * gv.x + bv.x;
  o.y = d1 * rstd * gv.y + bv.y;
  o.z = d2 * rstd * gv.z + bv.z;
  o.w = d3 * rstd * gv.w + bv.w;
  *(float4*)(out + (size_t)row * 1024 + t * 4) = o;
}

extern "C" void kernel_launch(void* const* d_in, const int* in_sizes, int n_in,
                              void* d_out, int out_size, void* d_ws, size_t ws_size,
                              hipStream_t stream) {
  const float* query = (const float*)d_in[0];
  const float* key_  = (const float*)d_in[1];
  const float* value = (const float*)d_in[2];
  const float* wq = (const float*)d_in[3];
  const float* bq = (const float*)d_in[4];
  const float* wk = (const float*)d_in[5];
  const float* bk = (const float*)d_in[6];
  const float* wv = (const float*)d_in[7];
  const float* bv = (const float*)d_in[8];
  const float* wo = (const float*)d_in[9];
  const float* bo = (const float*)d_in[10];
  const float* w1 = (const float*)d_in[11];
  const float* b1 = (const float*)d_in[12];
  const float* w2 = (const float*)d_in[13];
  const float* b2 = (const float*)d_in[14];
  const float* lam = (const float*)d_in[15];
  const float* lng = (const float*)d_in[16];
  const float* lnb = (const float*)d_in[17];

  char* ws = (char*)d_ws;
  size_t off = 0;
  auto alloc = [&](size_t n) { char* p = ws + off; off += (n + 255) & ~(size_t)255; return p; };
  unsigned short* qb  = (unsigned short*)alloc(8388608);   // query bf16 [4096,1024]
  unsigned short* kb  = (unsigned short*)alloc(8388608);
  unsigned short* vb  = (unsigned short*)alloc(8388608);
  unsigned short* wqb = (unsigned short*)alloc(2097152);
  unsigned short* wkb = (unsigned short*)alloc(2097152);
  unsigned short* wvb = (unsigned short*)alloc(2097152);
  unsigned short* wob = (unsigned short*)alloc(2097152);
  unsigned short* w1b = (unsigned short*)alloc(1048576);
  unsigned short* Qp  = (unsigned short*)alloc(8388608);   // projected Q (pre-scaled by 0.125*log2e) bf16
  unsigned short* Kp  = (unsigned short*)alloc(8388608);
  unsigned short* Vt  = (unsigned short*)alloc(8388608);   // V^T bf16 [1024 d_model][4096 tokens]
  unsigned short* h1q = (unsigned short*)alloc(4194304);   // gelu(x@w1^T) bf16 [4096,512]
  unsigned short* h1k = (unsigned short*)alloc(4194304);
  float* vadq = (float*)alloc(49152);                      // [4096,3]
  float* vadk = (float*)alloc(49152);
  unsigned short* Obuf = (unsigned short*)alloc(8388608);  // attention out bf16
  // aliases (stream-ordered lifetimes): aff over vb (dead after gemmV); tmp over qb+kb (dead after gemmH1)
  unsigned short* aff = vb;                                // [4][1024 k][1024 q] bf16, log2e-scaled
  float* tmp = (float*)qb;                                 // Wo out fp32 [4096,1024]

  cvt_k<<<dim3(2048, 3), 256, 0, stream>>>(query, key_, value, value, qb, kb, vb, vb, 4194304);
  cvt_k<<<dim3(512, 4), 256, 0, stream>>>(wq, wk, wv, wo, wqb, wkb, wvb, wob, 1048576);
  cvt_k<<<dim3(256, 1), 256, 0, stream>>>(w1, w1, w1, w1, w1b, w1b, w1b, w1b, 524288);

  // Q/K projections batched; Q pre-scaled by SCALE*log2e (exp2-domain softmax)
  gemm_k<0><<<dim3(8, 32, 2), 256, 0, stream>>>(qb, kb, wqb, wkb, bq, bk, Qp, Kp,
                                                4096, 1024, 1024, 0.125f * LOG2E, 1.f);
  // V^T directly: C'[d_model][token] = Wv @ X^T (row-bias)
  gemm_k<3><<<dim3(32, 8, 1), 256, 0, stream>>>(wvb, wvb, vb, vb, bv, bv, Vt, Vt,
                                                1024, 4096, 1024, 1.f, 1.f);
  // VAD layer 1 (GELU) batched for query/key
  gemm_k<1><<<dim3(4, 32, 2), 256, 0, stream>>>(qb, kb, w1b, w1b, b1, b1, h1q, h1k,
                                                4096, 512, 1024, 1.f, 1.f);
  vad2_k<<<dim3(1024, 2), 256, 0, stream>>>(h1q, h1k, w2, b2, vadq, vadk);
  aff_k<<<dim3(16, 16, 4), 256, 0, stream>>>(vadq, vadk, lam, aff);
  attn_k<<<dim3(16, 16, 4), 256, 0, stream>>>(Qp, Kp, Vt, aff, Obuf);
  gemm_k<2><<<dim3(8, 32, 1), 256, 0, stream>>>(Obuf, Obuf, wob, wob, bo, bo, tmp, tmp,
                                                4096, 1024, 1024, 1.f, 1.f);
  ln_k<<<4096, 256, 0, stream>>>(query, tmp, lng, lnb, (float*)d_out);
}

// Round 4
// 202.837 us; speedup vs baseline: 1.6553x; 1.0862x over previous
//
#include <hip/hip_runtime.h>
#include <hip/hip_bf16.h>

typedef float f32x4 __attribute__((ext_vector_type(4)));
typedef __bf16 bf16x8 __attribute__((ext_vector_type(8)));
typedef unsigned short us8 __attribute__((ext_vector_type(8)));
typedef unsigned short us4 __attribute__((ext_vector_type(4)));

#define DEVI __device__ __forceinline__
#define LOG2E 1.44269504088896f

DEVI unsigned short f2bf(float x) {
  return __builtin_bit_cast(unsigned short, __float2bfloat16(x));
}
DEVI float bf2f(unsigned short u) {
  return __builtin_bit_cast(float, ((unsigned int)u) << 16);
}
DEVI bf16x8 ldb8(const unsigned short* p) {
  return __builtin_bit_cast(bf16x8, *(const us8*)p);
}
DEVI void gload16(const unsigned short* g, unsigned short* l) {
  __builtin_amdgcn_global_load_lds(
      (const __attribute__((address_space(1))) unsigned int*)(const void*)g,
      (__attribute__((address_space(3))) unsigned int*)(void*)l, 16, 0, 0);
}

// ---------------- fp32 -> bf16 convert, 4-way batched via grid.y ----------------
__global__ __launch_bounds__(256) void cvt_k(const float* __restrict__ p0, const float* __restrict__ p1,
                                             const float* __restrict__ p2, const float* __restrict__ p3,
                                             unsigned short* __restrict__ o0, unsigned short* __restrict__ o1,
                                             unsigned short* __restrict__ o2, unsigned short* __restrict__ o3,
                                             int n) {
  const float* in;
  unsigned short* out;
  switch (blockIdx.y) {
    case 0: in = p0; out = o0; break;
    case 1: in = p1; out = o1; break;
    case 2: in = p2; out = o2; break;
    default: in = p3; out = o3; break;
  }
  int i = (blockIdx.x * 256 + threadIdx.x) * 8;
  if (i >= n) return;
  float4 a = *(const float4*)(in + i);
  float4 b = *(const float4*)(in + i + 4);
  us8 r = {f2bf(a.x), f2bf(a.y), f2bf(a.z), f2bf(a.w), f2bf(b.x), f2bf(b.y), f2bf(b.z), f2bf(b.w)};
  *(us8*)(out + i) = r;
}

// ---------------- GEMM (m97 structure, BK=64, XOR-swizzled LDS): C = A @ W^T + bias ----------------
// EPI: 0 = bf16 col-bias; 1 = GELU bf16 col-bias; 2 = f32 col-bias; 3 = bf16 ROW-bias
template <int EPI>
__global__ __launch_bounds__(256) void gemm_k(const unsigned short* __restrict__ A0, const unsigned short* __restrict__ A1,
                                              const unsigned short* __restrict__ W0, const unsigned short* __restrict__ W1,
                                              const float* __restrict__ bias0, const float* __restrict__ bias1,
                                              void* __restrict__ C0, void* __restrict__ C1,
                                              int M, int N, int K, float os0, float os1) {
  const unsigned short* A = blockIdx.z ? A1 : A0;
  const unsigned short* W = blockIdx.z ? W1 : W0;
  const float* bias = blockIdx.z ? bias1 : bias0;
  void* Cout = blockIdx.z ? (void*)C1 : (void*)C0;
  const float oscale = blockIdx.z ? os1 : os0;
  __shared__ unsigned short As[8192];  // [128][64] bf16, chunk ^= row&7 swizzle
  __shared__ unsigned short Bs[8192];
  // T1: XCD-aware block swizzle (nwg multiple of 8 in all our launches)
  const int nx = gridDim.x;
  const int lin = blockIdx.y * nx + blockIdx.x;
  const int cpx = (nx * gridDim.y) >> 3;
  const int nl = (lin & 7) * cpx + (lin >> 3);
  const int bx = nl % nx, by = nl / nx;
  const int t = threadIdx.x, l = t & 63;
  const int w4 = t >> 6, wr = w4 >> 1, wc = w4 & 1;
  const int l4 = l & 15, lg = l >> 4;
  const int brow = by * 128, bcol = bx * 128;
  f32x4 acc[4][4] = {};
  for (int kt = 0; kt < K; kt += 64) {
    __syncthreads();
#pragma unroll
    for (int i = 0; i < 4; ++i) {
      int c = t + i * 256;                     // 1024 chunks of 16B per operand
      int row = c >> 3, sw = ((c & 7) ^ (row & 7)) * 8;
      gload16(A + (size_t)(brow + row) * K + kt + sw, As + c * 8);
      gload16(W + (size_t)(bcol + row) * K + kt + sw, Bs + c * 8);
    }
    __syncthreads();
#pragma unroll
    for (int ks = 0; ks < 2; ++ks) {
      bf16x8 af[4], bfr[4];
#pragma unroll
      for (int mi = 0; mi < 4; ++mi)
        af[mi] = ldb8(&As[(wr * 64 + mi * 16 + l4) * 64 + (((ks * 4 + lg) ^ (l4 & 7))) * 8]);
#pragma unroll
      for (int ni = 0; ni < 4; ++ni)
        bfr[ni] = ldb8(&Bs[(wc * 64 + ni * 16 + l4) * 64 + (((ks * 4 + lg) ^ (l4 & 7))) * 8]);
#pragma unroll
      for (int mi = 0; mi < 4; ++mi)
#pragma unroll
        for (int ni = 0; ni < 4; ++ni)
          acc[mi][ni] = __builtin_amdgcn_mfma_f32_16x16x32_bf16(af[mi], bfr[ni], acc[mi][ni], 0, 0, 0);
    }
  }
#pragma unroll
  for (int mi = 0; mi < 4; ++mi)
#pragma unroll
    for (int ni = 0; ni < 4; ++ni) {
      int row0 = brow + wr * 64 + mi * 16 + lg * 4;
      int col = bcol + wc * 64 + ni * 16 + l4;
#pragma unroll
      for (int r = 0; r < 4; ++r) {
        float v;
        if (EPI == 3)
          v = (acc[mi][ni][r] + bias[row0 + r]) * oscale;
        else
          v = (acc[mi][ni][r] + bias[col]) * oscale;
        if (EPI == 1) v = 0.5f * v * (1.0f + erff(v * 0.70710678118f));
        if (EPI == 2)
          ((float*)Cout)[(size_t)(row0 + r) * N + col] = v;
        else
          ((unsigned short*)Cout)[(size_t)(row0 + r) * N + col] = f2bf(v);
      }
    }
}

// ---------------- VAD layer 2 (batched grid.y) ----------------
__global__ __launch_bounds__(256) void vad2_k(const unsigned short* __restrict__ h1a, const unsigned short* __restrict__ h1b,
                                              const float* __restrict__ w2, const float* __restrict__ b2,
                                              float* __restrict__ outa, float* __restrict__ outb) {
  const unsigned short* h1 = blockIdx.y ? h1b : h1a;
  float* out = blockIdx.y ? outb : outa;
  const int t = threadIdx.x, l = t & 63, w = t >> 6;
  const int row = blockIdx.x * 4 + w;
  us8 hv = *(const us8*)(h1 + (size_t)row * 512 + l * 8);
  float hf[8];
#pragma unroll
  for (int j = 0; j < 8; ++j) hf[j] = bf2f(hv[j]);
  float s[3];
#pragma unroll
  for (int c = 0; c < 3; ++c) {
    const float* wp = w2 + c * 512 + l * 8;
    float a = 0.f;
#pragma unroll
    for (int j = 0; j < 8; ++j) a += hf[j] * wp[j];
    s[c] = a;
  }
#pragma unroll
  for (int m = 1; m < 64; m <<= 1) {
#pragma unroll
    for (int c = 0; c < 3; ++c) s[c] += __shfl_xor(s[c], m, 64);
  }
  if (l == 0) {
#pragma unroll
    for (int c = 0; c < 3; ++c) out[(size_t)row * 3 + c] = tanhf(s[c] + b2[c]);
  }
}

// ---------------- affinity precompute, TRANSPOSED + log2e-scaled: aff[b][k][q] ----------------
__global__ __launch_bounds__(256) void aff_k(const float* __restrict__ vq, const float* __restrict__ vk,
                                             const float* __restrict__ plam, unsigned short* __restrict__ aff) {
  __shared__ float vqs[64][3], vks[64][3];
  const int t = threadIdx.x;
  const int b = blockIdx.z, q0 = blockIdx.y * 64, k0 = blockIdx.x * 64;
  const float lam2 = plam[0] * LOG2E;
  if (t < 192) {
    ((float*)vqs)[t] = vq[((size_t)b * 1024 + q0) * 3 + t];
    ((float*)vks)[t] = vk[((size_t)b * 1024 + k0) * 3 + t];
  }
  __syncthreads();
  const int k = t >> 2, qc = (t & 3) * 16;
  const float k0f = vks[k][0], k1f = vks[k][1], k2f = vks[k][2];
  unsigned short o[16];
#pragma unroll
  for (int j = 0; j < 16; ++j) {
    int q = qc + j;
    float dx = vqs[q][0] - k0f, dy = vqs[q][1] - k1f, dz = vqs[q][2] - k2f;
    o[j] = f2bf(-lam2 * sqrtf(dx * dx + dy * dy + dz * dz));
  }
  unsigned short* dst = aff + ((size_t)(b * 1024 + k0 + k)) * 1024 + q0 + qc;
  *(us8*)dst = *(us8*)&o[0];
  *(us8*)(dst + 8) = *(us8*)&o[8];
}

// ---------------- flash attention: 2-phase dbuf, 40KB LDS (4 blocks/CU), Q in regs ----------------
__global__ __launch_bounds__(256, 4) void attn_k(const unsigned short* __restrict__ Qp,
                                                 const unsigned short* __restrict__ Kp,
                                                 const unsigned short* __restrict__ Vt,
                                                 const unsigned short* __restrict__ aff,
                                                 unsigned short* __restrict__ Obuf) {
  __shared__ unsigned short Ks[2][4096];  // [64][64] bf16, chunk ^= row&7
  __shared__ unsigned short Vs[2][4096];  // logical [d][token]
  __shared__ unsigned short Ps[4][16][64];  // per-wave P transpose, chunk ^= row&7
  // XCD swizzle: all 16 q-blocks x 8 heads of one b stay on one XCD (shared K/V panel in L2)
  const int lin = blockIdx.x + 16 * (blockIdx.y + 16 * blockIdx.z);  // 1024 blocks
  const int nl = (lin & 7) * 128 + (lin >> 3);
  const int qb = nl & 15, h = (nl >> 4) & 15, b = nl >> 8;
  const int t = threadIdx.x, l = t & 63, w = t >> 6;
  const int l4 = l & 15, lg = l >> 4;
  const size_t qrow0 = (size_t)b * 1024 + qb * 64;
  const int hoff = h * 64;

  // Q fragments: straight to registers (read-once)
  bf16x8 qf[2];
#pragma unroll
  for (int ks = 0; ks < 2; ++ks)
    qf[ks] = ldb8(Qp + (qrow0 + w * 16 + l4) * 1024 + hoff + ks * 32 + lg * 8);

  // prologue: stage K/V tile 0
  {
    const unsigned short* gk = Kp + ((size_t)b * 1024) * 1024 + hoff;
    const unsigned short* gv = Vt + (size_t)hoff * 4096 + (size_t)b * 1024;
#pragma unroll
    for (int i = 0; i < 2; ++i) {
      int c = t + i * 256;
      int row = c >> 3, sw = ((c & 7) ^ (row & 7)) * 8;
      gload16(gk + (size_t)row * 1024 + sw, Ks[0] + c * 8);
      gload16(gv + (size_t)row * 4096 + sw, Vs[0] + c * 8);
    }
  }
  float m_run[4], l_run[4];
  f32x4 accO[4] = {};
#pragma unroll
  for (int r = 0; r < 4; ++r) { m_run[r] = -1e30f; l_run[r] = 0.f; }
  // transposed aff base: aff[(b*1024 + k)*1024 + q], us4 over r
  const unsigned short* ab = aff + ((size_t)b * 1024 + l4) * 1024 + qb * 64 + w * 16 + lg * 4;
  __syncthreads();

  int cur = 0;
  for (int kt = 0; kt < 16; ++kt) {
    // issue next-tile stage FIRST: latency hides under this tile's compute
    if (kt < 15) {
      const unsigned short* gk = Kp + ((size_t)b * 1024 + (kt + 1) * 64) * 1024 + hoff;
      const unsigned short* gv = Vt + (size_t)hoff * 4096 + (size_t)b * 1024 + (kt + 1) * 64;
#pragma unroll
      for (int i = 0; i < 2; ++i) {
        int c = t + i * 256;
        int row = c >> 3, sw = ((c & 7) ^ (row & 7)) * 8;
        gload16(gk + (size_t)row * 1024 + sw, Ks[cur ^ 1] + c * 8);
        gload16(gv + (size_t)row * 4096 + sw, Vs[cur ^ 1] + c * 8);
      }
    }
    // affinity (bf16, transposed layout -> one us4 per jt)
    float aval[4][4];
#pragma unroll
    for (int jt = 0; jt < 4; ++jt) {
      us4 av = *(const us4*)(ab + (size_t)(kt * 64 + jt * 16) * 1024);
#pragma unroll
      for (int r = 0; r < 4; ++r) aval[jt][r] = bf2f(av[r]);
    }
    // QK^T (Q pre-scaled by SCALE*log2e)
    f32x4 sc[4] = {};
    __builtin_amdgcn_s_setprio(1);
#pragma unroll
    for (int jt = 0; jt < 4; ++jt) {
#pragma unroll
      for (int ks = 0; ks < 2; ++ks) {
        bf16x8 kf = ldb8(&Ks[cur][(jt * 16 + l4) * 64 + (((ks * 4 + lg) ^ (l4 & 7))) * 8]);
        sc[jt] = __builtin_amdgcn_mfma_f32_16x16x32_bf16(qf[ks], kf, sc[jt], 0, 0, 0);
      }
    }
    __builtin_amdgcn_s_setprio(0);
    // guided scores + online softmax in exp2 domain
    float pv[4][4], vmax[4];
#pragma unroll
    for (int r = 0; r < 4; ++r) vmax[r] = -1e30f;
#pragma unroll
    for (int jt = 0; jt < 4; ++jt)
#pragma unroll
      for (int r = 0; r < 4; ++r) {
        float s = sc[jt][r] + aval[jt][r];
        pv[jt][r] = s;
        vmax[r] = fmaxf(vmax[r], s);
      }
#pragma unroll
    for (int m = 1; m < 16; m <<= 1) {
#pragma unroll
      for (int r = 0; r < 4; ++r) vmax[r] = fmaxf(vmax[r], __shfl_xor(vmax[r], m, 64));
    }
    float fs[4], rs[4];
#pragma unroll
    for (int r = 0; r < 4; ++r) {
      float mn = fmaxf(m_run[r], vmax[r]);
      fs[r] = exp2f(m_run[r] - mn);
      m_run[r] = mn;
      rs[r] = 0.f;
#pragma unroll
      for (int jt = 0; jt < 4; ++jt) { pv[jt][r] = exp2f(pv[jt][r] - mn); rs[r] += pv[jt][r]; }
    }
#pragma unroll
    for (int m = 1; m < 16; m <<= 1) {
#pragma unroll
      for (int r = 0; r < 4; ++r) rs[r] += __shfl_xor(rs[r], m, 64);
    }
#pragma unroll
    for (int r = 0; r < 4; ++r) l_run[r] = l_run[r] * fs[r] + rs[r];
#pragma unroll
    for (int dt = 0; dt < 4; ++dt)
#pragma unroll
      for (int r = 0; r < 4; ++r) accO[dt][r] = accO[dt][r] * fs[r];
    // transpose P through per-wave LDS (C-layout -> A-fragment layout), XOR-swizzled
#pragma unroll
    for (int jt = 0; jt < 4; ++jt)
#pragma unroll
      for (int r = 0; r < 4; ++r) {
        int row = lg * 4 + r, col = jt * 16 + l4;
        Ps[w][row][(((col >> 3) ^ (row & 7)) << 3) | (col & 7)] = f2bf(pv[jt][r]);
      }
    // PV from transposed V
    __builtin_amdgcn_s_setprio(1);
#pragma unroll
    for (int js = 0; js < 2; ++js) {
      bf16x8 pa = ldb8(&Ps[w][l4][(((js * 4 + lg) ^ (l4 & 7))) * 8]);
#pragma unroll
      for (int dt = 0; dt < 4; ++dt) {
        bf16x8 vf = ldb8(&Vs[cur][(dt * 16 + l4) * 64 + (((js * 4 + lg) ^ (l4 & 7))) * 8]);
        accO[dt] = __builtin_amdgcn_mfma_f32_16x16x32_bf16(pa, vf, accO[dt], 0, 0, 0);
      }
    }
    __builtin_amdgcn_s_setprio(0);
    __syncthreads();  // single barrier per tile: drains next-tile stage, frees buf for overwrite
    cur ^= 1;
  }
#pragma unroll
  for (int r = 0; r < 4; ++r) l_run[r] = 1.f / l_run[r];
#pragma unroll
  for (int dt = 0; dt < 4; ++dt)
#pragma unroll
    for (int r = 0; r < 4; ++r) {
      float v = accO[dt][r] * l_run[r];
      Obuf[(qrow0 + w * 16 + lg * 4 + r) * 1024 + hoff + dt * 16 + l4] = f2bf(v);
    }
}

// ---------------- residual + layernorm ----------------
__global__ __launch_bounds__(256) void ln_k(const float* __restrict__ q,
                                            const float* __restrict__ tin,
                                            const float* __restrict__ g,
                                            const float* __restrict__ bb,
                                            float* __restrict__ out) {
  __shared__ float red[8];
  const int row = blockIdx.x, t = threadIdx.x;
  const int l = t & 63, w = t >> 6;
  const size_t base = (size_t)row * 1024 + t * 4;
  float4 a = *(const float4*)(q + base);
  float4 c = *(const float4*)(tin + base);
  float x0 = a.x + c.x, x1 = a.y + c.y, x2 = a.z + c.z, x3 = a.w + c.w;
  float s = x0 + x1 + x2 + x3;
#pragma unroll
  for (int m = 1; m < 64; m <<= 1) s += __shfl_xor(s, m, 64);
  if (l == 0) red[w] = s;
  __syncthreads();
  float mean = (red[0] + red[1] + red[2] + red[3]) * (1.f / 1024.f);
  float d0 = x0 - mean, d1 = x1 - mean, d2 = x2 - mean, d3 = x3 - mean;
  float v = d0 * d0 + d1 * d1 + d2 * d2 + d3 * d3;
#pragma unroll
  for (int m = 1; m < 64; m <<= 1) v += __shfl_xor(v, m, 64);
  if (l == 0) red[4 + w] = v;
  __syncthreads();
  float var = (red[4] + red[5] + red[6] + red[7]) * (1.f / 1024.f);
  float rstd = rsqrtf(var + 1e-5f);
  float4 gv = *(const float4*)(g + t * 4);
  float4 bv = *(const float4*)(bb + t * 4);
  float4 o;
  o.x = d0 * rstd * gv.x + bv.x;
  o.y = d1 * rstd * gv.y + bv.y;
  o.z = d2 * rstd * gv.z + bv.z;
  o.w = d3 * rstd * gv.w + bv.w;
  *(float4*)(out + (size_t)row * 1024 + t * 4) = o;
}

extern "C" void kernel_launch(void* const* d_in, const int* in_sizes, int n_in,
                              void* d_out, int out_size, void* d_ws, size_t ws_size,
                              hipStream_t stream) {
  const float* query = (const float*)d_in[0];
  const float* key_  = (const float*)d_in[1];
  const float* value = (const float*)d_in[2];
  const float* wq = (const float*)d_in[3];
  const float* bq = (const float*)d_in[4];
  const float* wk = (const float*)d_in[5];
  const float* bk = (const float*)d_in[6];
  const float* wv = (const float*)d_in[7];
  const float* bv = (const float*)d_in[8];
  const float* wo = (const float*)d_in[9];
  const float* bo = (const float*)d_in[10];
  const float* w1 = (const float*)d_in[11];
  const float* b1 = (const float*)d_in[12];
  const float* w2 = (const float*)d_in[13];
  const float* b2 = (const float*)d_in[14];
  const float* lam = (const float*)d_in[15];
  const float* lng = (const float*)d_in[16];
  const float* lnb = (const float*)d_in[17];

  char* ws = (char*)d_ws;
  size_t off = 0;
  auto alloc = [&](size_t n) { char* p = ws + off; off += (n + 255) & ~(size_t)255; return p; };
  unsigned short* qb  = (unsigned short*)alloc(8388608);   // query bf16 [4096,1024]
  unsigned short* kb  = (unsigned short*)alloc(8388608);
  unsigned short* vb  = (unsigned short*)alloc(8388608);
  unsigned short* wqb = (unsigned short*)alloc(2097152);
  unsigned short* wkb = (unsigned short*)alloc(2097152);
  unsigned short* wvb = (unsigned short*)alloc(2097152);
  unsigned short* wob = (unsigned short*)alloc(2097152);
  unsigned short* w1b = (unsigned short*)alloc(1048576);
  unsigned short* Qp  = (unsigned short*)alloc(8388608);   // projected Q (pre-scaled by 0.125*log2e) bf16
  unsigned short* Kp  = (unsigned short*)alloc(8388608);
  unsigned short* Vt  = (unsigned short*)alloc(8388608);   // V^T bf16 [1024 d_model][4096 tokens]
  unsigned short* h1q = (unsigned short*)alloc(4194304);   // gelu(x@w1^T) bf16 [4096,512]
  unsigned short* h1k = (unsigned short*)alloc(4194304);
  float* vadq = (float*)alloc(49152);                      // [4096,3]
  float* vadk = (float*)alloc(49152);
  unsigned short* Obuf = (unsigned short*)alloc(8388608);  // attention out bf16
  // aliases (stream-ordered lifetimes): aff over vb (dead after gemmV); tmp over qb+kb (dead after gemmH1)
  unsigned short* aff = vb;                                // [4][1024 k][1024 q] bf16, log2e-scaled
  float* tmp = (float*)qb;                                 // Wo out fp32 [4096,1024]

  cvt_k<<<dim3(2048, 3), 256, 0, stream>>>(query, key_, value, value, qb, kb, vb, vb, 4194304);
  cvt_k<<<dim3(512, 4), 256, 0, stream>>>(wq, wk, wv, wo, wqb, wkb, wvb, wob, 1048576);
  cvt_k<<<dim3(256, 1), 256, 0, stream>>>(w1, w1, w1, w1, w1b, w1b, w1b, w1b, 524288);

  // Q/K projections batched; Q pre-scaled by SCALE*log2e (exp2-domain softmax)
  gemm_k<0><<<dim3(8, 32, 2), 256, 0, stream>>>(qb, kb, wqb, wkb, bq, bk, Qp, Kp,
                                                4096, 1024, 1024, 0.125f * LOG2E, 1.f);
  // V^T directly: C'[d_model][token] = Wv @ X^T (row-bias)
  gemm_k<3><<<dim3(32, 8, 1), 256, 0, stream>>>(wvb, wvb, vb, vb, bv, bv, Vt, Vt,
                                                1024, 4096, 1024, 1.f, 1.f);
  // VAD layer 1 (GELU) batched for query/key
  gemm_k<1><<<dim3(4, 32, 2), 256, 0, stream>>>(qb, kb, w1b, w1b, b1, b1, h1q, h1k,
                                                4096, 512, 1024, 1.f, 1.f);
  vad2_k<<<dim3(1024, 2), 256, 0, stream>>>(h1q, h1k, w2, b2, vadq, vadk);
  aff_k<<<dim3(16, 16, 4), 256, 0, stream>>>(vadq, vadk, lam, aff);
  attn_k<<<dim3(16, 16, 4), 256, 0, stream>>>(Qp, Kp, Vt, aff, Obuf);
  gemm_k<2><<<dim3(8, 32, 1), 256, 0, stream>>>(Obuf, Obuf, wob, wob, bo, bo, tmp, tmp,
                                                4096, 1024, 1024, 1.f, 1.f);
  ln_k<<<4096, 256, 0, stream>>>(query, tmp, lng, lnb, (float*)d_out);
}

// Round 5
// 166.515 us; speedup vs baseline: 2.0163x; 1.2181x over previous
//
#include <hip/hip_runtime.h>
#include <hip/hip_bf16.h>

typedef float f32x4 __attribute__((ext_vector_type(4)));
typedef __bf16 bf16x8 __attribute__((ext_vector_type(8)));
typedef unsigned short us8 __attribute__((ext_vector_type(8)));
typedef unsigned short us4 __attribute__((ext_vector_type(4)));

#define DEVI __device__ __forceinline__
#define LOG2E 1.44269504088896f

DEVI unsigned short f2bf(float x) {
  return __builtin_bit_cast(unsigned short, __float2bfloat16(x));
}
DEVI float bf2f(unsigned short u) {
  return __builtin_bit_cast(float, ((unsigned int)u) << 16);
}
DEVI bf16x8 ldb8(const unsigned short* p) {
  return __builtin_bit_cast(bf16x8, *(const us8*)p);
}
DEVI void gload16(const unsigned short* g, unsigned short* l) {
  __builtin_amdgcn_global_load_lds(
      (const __attribute__((address_space(1))) unsigned int*)(const void*)g,
      (__attribute__((address_space(3))) unsigned int*)(void*)l, 16, 0, 0);
}

// ---------------- fp32 -> bf16 converts ----------------
__global__ __launch_bounds__(256) void cvt3_k(const float* __restrict__ p0, const float* __restrict__ p1,
                                              const float* __restrict__ p2,
                                              unsigned short* __restrict__ o0, unsigned short* __restrict__ o1,
                                              unsigned short* __restrict__ o2, int n) {
  const float* in;
  unsigned short* out;
  switch (blockIdx.y) {
    case 0: in = p0; out = o0; break;
    case 1: in = p1; out = o1; break;
    default: in = p2; out = o2; break;
  }
  int i = (blockIdx.x * 256 + threadIdx.x) * 8;
  if (i >= n) return;
  float4 a = *(const float4*)(in + i);
  float4 b = *(const float4*)(in + i + 4);
  us8 r = {f2bf(a.x), f2bf(a.y), f2bf(a.z), f2bf(a.w), f2bf(b.x), f2bf(b.y), f2bf(b.z), f2bf(b.w)};
  *(us8*)(out + i) = r;
}

__global__ __launch_bounds__(256) void cvt5_k(const float* __restrict__ p0, const float* __restrict__ p1,
                                              const float* __restrict__ p2, const float* __restrict__ p3,
                                              const float* __restrict__ p4,
                                              unsigned short* __restrict__ o0, unsigned short* __restrict__ o1,
                                              unsigned short* __restrict__ o2, unsigned short* __restrict__ o3,
                                              unsigned short* __restrict__ o4) {
  const float* in;
  unsigned short* out;
  int n = 1048576;
  switch (blockIdx.y) {
    case 0: in = p0; out = o0; break;
    case 1: in = p1; out = o1; break;
    case 2: in = p2; out = o2; break;
    case 3: in = p3; out = o3; break;
    default: in = p4; out = o4; n = 524288; break;
  }
  int i = (blockIdx.x * 256 + threadIdx.x) * 8;
  if (i >= n) return;
  float4 a = *(const float4*)(in + i);
  float4 b = *(const float4*)(in + i + 4);
  us8 r = {f2bf(a.x), f2bf(a.y), f2bf(a.z), f2bf(a.w), f2bf(b.x), f2bf(b.y), f2bf(b.z), f2bf(b.w)};
  *(us8*)(out + i) = r;
}

// ---------------- GEMM body (m97 structure, BK=64, XOR-swizzled LDS): C = A @ W^T + bias ----------------
// EPI: 0 = bf16 col-bias; 1 = GELU bf16 col-bias; 2 = f32 out, col-bias*0.5 (split-K half); 3 = bf16 ROW-bias
template <int EPI>
DEVI void gemm_body(const unsigned short* __restrict__ A, const unsigned short* __restrict__ W,
                    const float* __restrict__ bias, void* __restrict__ Cout,
                    int N, int K, int lda, float oscale, int brow, int bcol,
                    unsigned short* As, unsigned short* Bs, int t) {
  const int l = t & 63;
  const int w4 = t >> 6, wr = w4 >> 1, wc = w4 & 1;
  const int l4 = l & 15, lg = l >> 4;
  f32x4 acc[4][4] = {};
  for (int kt = 0; kt < K; kt += 64) {
    __syncthreads();
#pragma unroll
    for (int i = 0; i < 4; ++i) {
      int c = t + i * 256;                     // 1024 chunks of 16B per operand
      int row = c >> 3, sw = ((c & 7) ^ (row & 7)) * 8;
      gload16(A + (size_t)(brow + row) * lda + kt + sw, As + c * 8);
      gload16(W + (size_t)(bcol + row) * lda + kt + sw, Bs + c * 8);
    }
    __syncthreads();
#pragma unroll
    for (int ks = 0; ks < 2; ++ks) {
      bf16x8 af[4], bfr[4];
#pragma unroll
      for (int mi = 0; mi < 4; ++mi)
        af[mi] = ldb8(&As[(wr * 64 + mi * 16 + l4) * 64 + (((ks * 4 + lg) ^ (l4 & 7))) * 8]);
#pragma unroll
      for (int ni = 0; ni < 4; ++ni)
        bfr[ni] = ldb8(&Bs[(wc * 64 + ni * 16 + l4) * 64 + (((ks * 4 + lg) ^ (l4 & 7))) * 8]);
#pragma unroll
      for (int mi = 0; mi < 4; ++mi)
#pragma unroll
        for (int ni = 0; ni < 4; ++ni)
          acc[mi][ni] = __builtin_amdgcn_mfma_f32_16x16x32_bf16(af[mi], bfr[ni], acc[mi][ni], 0, 0, 0);
    }
  }
#pragma unroll
  for (int mi = 0; mi < 4; ++mi)
#pragma unroll
    for (int ni = 0; ni < 4; ++ni) {
      int row0 = brow + wr * 64 + mi * 16 + lg * 4;
      int col = bcol + wc * 64 + ni * 16 + l4;
#pragma unroll
      for (int r = 0; r < 4; ++r) {
        float v;
        if (EPI == 3)
          v = (acc[mi][ni][r] + bias[row0 + r]) * oscale;
        else if (EPI == 2)
          v = acc[mi][ni][r] + 0.5f * bias[col];
        else
          v = (acc[mi][ni][r] + bias[col]) * oscale;
        if (EPI == 1) v = 0.5f * v * (1.0f + erff(v * 0.70710678118f));
        if (EPI == 2)
          ((float*)Cout)[(size_t)(row0 + r) * N + col] = v;
        else
          ((unsigned short*)Cout)[(size_t)(row0 + r) * N + col] = f2bf(v);
      }
    }
}

// ---------------- fused projections: Q-proj | K-proj | V^T | h1q | h1k in one 1024-block launch ----------------
__global__ __launch_bounds__(256) void proj_k(const unsigned short* __restrict__ qb, const unsigned short* __restrict__ kb,
                                              const unsigned short* __restrict__ vb,
                                              const unsigned short* __restrict__ wqb, const unsigned short* __restrict__ wkb,
                                              const unsigned short* __restrict__ wvb, const unsigned short* __restrict__ w1b,
                                              const float* __restrict__ bq, const float* __restrict__ bk,
                                              const float* __restrict__ bv, const float* __restrict__ b1,
                                              unsigned short* __restrict__ Qp, unsigned short* __restrict__ Kp,
                                              unsigned short* __restrict__ Vt,
                                              unsigned short* __restrict__ h1q, unsigned short* __restrict__ h1k) {
  __shared__ unsigned short As[8192];
  __shared__ unsigned short Bs[8192];
  const int t = threadIdx.x;
  const int lin = blockIdx.x;                 // 1024 blocks
  const int nl = (lin & 7) * 128 + (lin >> 3);  // XCD swizzle: each XCD gets one contiguous range
  if (nl < 256) {        // Q projection (pre-scaled by SCALE*log2e), 8x32
    gemm_body<0>(qb, wqb, bq, Qp, 1024, 1024, 1024, 0.125f * LOG2E,
                 (nl >> 3) * 128, (nl & 7) * 128, As, Bs, t);
  } else if (nl < 512) { // K projection, 8x32
    int s = nl - 256;
    gemm_body<0>(kb, wkb, bk, Kp, 1024, 1024, 1024, 1.f,
                 (s >> 3) * 128, (s & 7) * 128, As, Bs, t);
  } else if (nl < 768) { // V^T = Wv @ X^T (row-bias), 32x8
    int s = nl - 512;
    gemm_body<3>(wvb, vb, bv, Vt, 4096, 1024, 1024, 1.f,
                 (s >> 5) * 128, (s & 31) * 128, As, Bs, t);
  } else {               // VAD layer 1 (GELU) for query / key, 4x32 x2
    int s = nl - 768;
    const unsigned short* A = (s >= 128) ? kb : qb;
    unsigned short* C = (s >= 128) ? h1k : h1q;
    int s2 = s & 127;
    gemm_body<1>(A, w1b, b1, C, 512, 1024, 1024, 1.f,
                 (s2 >> 2) * 128, (s2 & 3) * 128, As, Bs, t);
  }
}

// ---------------- Wo GEMM, split-K x2 (512 blocks): tmpA = Obuf[:, :512]@Wo^T + b/2, tmpB = other half ----------------
__global__ __launch_bounds__(256) void wo_k(const unsigned short* __restrict__ Obuf, const unsigned short* __restrict__ wob,
                                            const float* __restrict__ bo,
                                            float* __restrict__ tmpA, float* __restrict__ tmpB) {
  __shared__ unsigned short As[8192];
  __shared__ unsigned short Bs[8192];
  const int t = threadIdx.x;
  const int lin = blockIdx.x;                 // 512 blocks
  const int nl = (lin & 7) * 64 + (lin >> 3);
  const int z = nl >> 8, s = nl & 255;
  gemm_body<2>(Obuf + z * 512, wob + z * 512, bo, z ? tmpB : tmpA,
               1024, 512, 1024, 1.f, (s >> 3) * 128, (s & 7) * 128, As, Bs, t);
}

// ---------------- VAD layer 2 (batched grid.y) ----------------
__global__ __launch_bounds__(256) void vad2_k(const unsigned short* __restrict__ h1a, const unsigned short* __restrict__ h1b,
                                              const float* __restrict__ w2, const float* __restrict__ b2,
                                              float* __restrict__ outa, float* __restrict__ outb) {
  const unsigned short* h1 = blockIdx.y ? h1b : h1a;
  float* out = blockIdx.y ? outb : outa;
  const int t = threadIdx.x, l = t & 63, w = t >> 6;
  const int row = blockIdx.x * 4 + w;
  us8 hv = *(const us8*)(h1 + (size_t)row * 512 + l * 8);
  float hf[8];
#pragma unroll
  for (int j = 0; j < 8; ++j) hf[j] = bf2f(hv[j]);
  float s[3];
#pragma unroll
  for (int c = 0; c < 3; ++c) {
    const float* wp = w2 + c * 512 + l * 8;
    float a = 0.f;
#pragma unroll
    for (int j = 0; j < 8; ++j) a += hf[j] * wp[j];
    s[c] = a;
  }
#pragma unroll
  for (int m = 1; m < 64; m <<= 1) {
#pragma unroll
    for (int c = 0; c < 3; ++c) s[c] += __shfl_xor(s[c], m, 64);
  }
  if (l == 0) {
#pragma unroll
    for (int c = 0; c < 3; ++c) out[(size_t)row * 3 + c] = tanhf(s[c] + b2[c]);
  }
}

// ---------------- affinity precompute, q-major + log2e-scaled: aff[b][q][k] ----------------
__global__ __launch_bounds__(256) void aff_k(const float* __restrict__ vq, const float* __restrict__ vk,
                                             const float* __restrict__ plam, unsigned short* __restrict__ aff) {
  __shared__ float vqs[64][3], vks[64][3];
  const int t = threadIdx.x;
  const int b = blockIdx.z, q0 = blockIdx.y * 64, k0 = blockIdx.x * 64;
  const float lam2 = plam[0] * LOG2E;
  if (t < 192) {
    ((float*)vqs)[t] = vq[((size_t)b * 1024 + q0) * 3 + t];
    ((float*)vks)[t] = vk[((size_t)b * 1024 + k0) * 3 + t];
  }
  __syncthreads();
  const int q = t >> 2, kc = (t & 3) * 16;
  const float a0 = vqs[q][0], a1 = vqs[q][1], a2 = vqs[q][2];
  unsigned short o[16];
#pragma unroll
  for (int j = 0; j < 16; ++j) {
    int k = kc + j;
    float dx = a0 - vks[k][0], dy = a1 - vks[k][1], dz = a2 - vks[k][2];
    o[j] = f2bf(-lam2 * sqrtf(dx * dx + dy * dy + dz * dz));
  }
  unsigned short* dst = aff + ((size_t)(b * 1024 + q0 + q)) * 1024 + k0 + kc;
  *(us8*)dst = *(us8*)&o[0];
  *(us8*)(dst + 8) = *(us8*)&o[8];
}

// ---------------- flash attention: swapped-QK lane-local softmax, 2-phase dbuf, defer-max ----------------
__global__ __launch_bounds__(256, 4) void attn_k(const unsigned short* __restrict__ Qp,
                                                 const unsigned short* __restrict__ Kp,
                                                 const unsigned short* __restrict__ Vt,
                                                 const unsigned short* __restrict__ aff,
                                                 unsigned short* __restrict__ Obuf) {
  __shared__ unsigned short Ks[2][4096];   // [64][64] bf16, chunk ^= row&7
  __shared__ unsigned short Vs[2][4096];   // logical [d][token]
  __shared__ unsigned short Ps[4][1024];   // per-wave [16 q-rows][64 k], 16B-chunk ^= (l4&7)
  const int lin = blockIdx.x + 16 * (blockIdx.y + 16 * blockIdx.z);  // 1024 blocks
  const int nl = (lin & 7) * 128 + (lin >> 3);
  const int qb = nl & 15, h = (nl >> 4) & 15, b = nl >> 8;
  const int t = threadIdx.x, l = t & 63, w = t >> 6;
  const int l4 = l & 15, lg = l >> 4;
  const size_t qrow0 = (size_t)b * 1024 + qb * 64;
  const int hoff = h * 64;

  // Q fragments straight to registers (read-once). Used as MFMA *B*-operand (swapped QK^T):
  // B-frag lane layout == A-frag lane layout (row=l4, k=lg*8+j), so reads are unchanged.
  bf16x8 qf[2];
#pragma unroll
  for (int ks = 0; ks < 2; ++ks)
    qf[ks] = ldb8(Qp + (qrow0 + w * 16 + l4) * 1024 + hoff + ks * 32 + lg * 8);

  // prologue: stage K/V tile 0
  {
    const unsigned short* gk = Kp + ((size_t)b * 1024) * 1024 + hoff;
    const unsigned short* gv = Vt + (size_t)hoff * 4096 + (size_t)b * 1024;
#pragma unroll
    for (int i = 0; i < 2; ++i) {
      int c = t + i * 256;
      int row = c >> 3, sw = ((c & 7) ^ (row & 7)) * 8;
      gload16(gk + (size_t)row * 1024 + sw, Ks[0] + c * 8);
      gload16(gv + (size_t)row * 4096 + sw, Vs[0] + c * 8);
    }
  }
  float m_run = -1e30f, l_run = 0.f;   // per-lane scalars: this lane's q-row = w*16 + l4
  f32x4 accO[4] = {};
  // q-major aff: lane reads its q-row, k contiguous
  const unsigned short* ab = aff + (qrow0 + w * 16 + l4) * 1024 + lg * 4;
  __syncthreads();

  int cur = 0;
  for (int kt = 0; kt < 16; ++kt) {
    // issue next-tile stage FIRST: latency hides under this tile's compute
    if (kt < 15) {
      const unsigned short* gk = Kp + ((size_t)b * 1024 + (kt + 1) * 64) * 1024 + hoff;
      const unsigned short* gv = Vt + (size_t)hoff * 4096 + (size_t)b * 1024 + (kt + 1) * 64;
#pragma unroll
      for (int i = 0; i < 2; ++i) {
        int c = t + i * 256;
        int row = c >> 3, sw = ((c & 7) ^ (row & 7)) * 8;
        gload16(gk + (size_t)row * 1024 + sw, Ks[cur ^ 1] + c * 8);
        gload16(gv + (size_t)row * 4096 + sw, Vs[cur ^ 1] + c * 8);
      }
    }
    // affinity: 4 contiguous 8B loads (k = kt*64 + jt*16 + lg*4 + r)
    float aval[4][4];
#pragma unroll
    for (int jt = 0; jt < 4; ++jt) {
      us4 av = *(const us4*)(ab + kt * 64 + jt * 16);
#pragma unroll
      for (int r = 0; r < 4; ++r) aval[jt][r] = bf2f(av[r]);
    }
    // QK^T with SWAPPED operands: sc[jt][r] = P[q = w*16+l4][k = kt*64 + jt*16 + lg*4 + r]
    f32x4 sc[4] = {};
    __builtin_amdgcn_s_setprio(1);
#pragma unroll
    for (int jt = 0; jt < 4; ++jt) {
#pragma unroll
      for (int ks = 0; ks < 2; ++ks) {
        bf16x8 kf = ldb8(&Ks[cur][(jt * 16 + l4) * 64 + (((ks * 4 + lg) ^ (l4 & 7))) * 8]);
        sc[jt] = __builtin_amdgcn_mfma_f32_16x16x32_bf16(kf, qf[ks], sc[jt], 0, 0, 0);
      }
    }
    __builtin_amdgcn_s_setprio(0);
    // lane-local online softmax (exp2 domain)
    float pv[4][4];
    float pm = -1e30f;
#pragma unroll
    for (int jt = 0; jt < 4; ++jt)
#pragma unroll
      for (int r = 0; r < 4; ++r) {
        float s = sc[jt][r] + aval[jt][r];
        pv[jt][r] = s;
        pm = fmaxf(pm, s);
      }
    pm = fmaxf(pm, __shfl_xor(pm, 16, 64));
    pm = fmaxf(pm, __shfl_xor(pm, 32, 64));
    if (__any(pm > m_run + 8.f)) {   // defer-max: rescale only when a row's max grew materially
      float mn = fmaxf(m_run, pm);
      float fs = exp2f(m_run - mn);
      m_run = mn;
      l_run *= fs;
      float fsr[4];
#pragma unroll
      for (int r = 0; r < 4; ++r) fsr[r] = __shfl(fs, lg * 4 + r, 16);  // to accO's q = lg*4+r domain
#pragma unroll
      for (int dt = 0; dt < 4; ++dt)
#pragma unroll
        for (int r = 0; r < 4; ++r) accO[dt][r] *= fsr[r];
    }
    float rs = 0.f;
#pragma unroll
    for (int jt = 0; jt < 4; ++jt)
#pragma unroll
      for (int r = 0; r < 4; ++r) { pv[jt][r] = exp2f(pv[jt][r] - m_run); rs += pv[jt][r]; }
    rs += __shfl_xor(rs, 16, 64);
    rs += __shfl_xor(rs, 32, 64);
    l_run += rs;
    // pack P to bf16 pairs, swizzled ds_write_b64 into Ps[w][q=l4][k]
    char* pw = (char*)&Ps[w][0];
#pragma unroll
    for (int jt = 0; jt < 4; ++jt) {
      unsigned int p0, p1;
      asm("v_cvt_pk_bf16_f32 %0, %1, %2" : "=v"(p0) : "v"(pv[jt][0]), "v"(pv[jt][1]));
      asm("v_cvt_pk_bf16_f32 %0, %1, %2" : "=v"(p1) : "v"(pv[jt][2]), "v"(pv[jt][3]));
      int chunk = (jt * 2 + (lg >> 1)) ^ (l4 & 7);
      *(unsigned long long*)(pw + l4 * 128 + chunk * 16 + (lg & 1) * 8) =
          (unsigned long long)p0 | ((unsigned long long)p1 << 32);
    }
    // PV: A-frag from Ps (row=l4, k=lg*8+j), B-frag from transposed V
    __builtin_amdgcn_s_setprio(1);
#pragma unroll
    for (int js = 0; js < 2; ++js) {
      bf16x8 pa = ldb8(&Ps[w][l4 * 64 + (((js * 4 + lg) ^ (l4 & 7))) * 8]);
#pragma unroll
      for (int dt = 0; dt < 4; ++dt) {
        bf16x8 vf = ldb8(&Vs[cur][(dt * 16 + l4) * 64 + (((js * 4 + lg) ^ (l4 & 7))) * 8]);
        accO[dt] = __builtin_amdgcn_mfma_f32_16x16x32_bf16(pa, vf, accO[dt], 0, 0, 0);
      }
    }
    __builtin_amdgcn_s_setprio(0);
    __syncthreads();  // single barrier per tile
    cur ^= 1;
  }
  // epilogue: transpose 1/l to accO's q-domain, normalize, store bf16
  float linv = 1.f / l_run;
  float lr[4];
#pragma unroll
  for (int r = 0; r < 4; ++r) lr[r] = __shfl(linv, lg * 4 + r, 16);
#pragma unroll
  for (int dt = 0; dt < 4; ++dt)
#pragma unroll
    for (int r = 0; r < 4; ++r) {
      float v = accO[dt][r] * lr[r];
      Obuf[(qrow0 + w * 16 + lg * 4 + r) * 1024 + hoff + dt * 16 + l4] = f2bf(v);
    }
}

// ---------------- residual + layernorm (3-input: query + tmpA + tmpB) ----------------
__global__ __launch_bounds__(256) void ln_k(const float* __restrict__ q,
                                            const float* __restrict__ ta,
                                            const float* __restrict__ tb,
                                            const float* __restrict__ g,
                                            const float* __restrict__ bb,
                                            float* __restrict__ out) {
  __shared__ float red[8];
  const int row = blockIdx.x, t = threadIdx.x;
  const int l = t & 63, w = t >> 6;
  const size_t base = (size_t)row * 1024 + t * 4;
  float4 a = *(const float4*)(q + base);
  float4 c = *(const float4*)(ta + base);
  float4 d = *(const float4*)(tb + base);
  float x0 = a.x + c.x + d.x, x1 = a.y + c.y + d.y, x2 = a.z + c.z + d.z, x3 = a.w + c.w + d.w;
  float s = x0 + x1 + x2 + x3;
#pragma unroll
  for (int m = 1; m < 64; m <<= 1) s += __shfl_xor(s, m, 64);
  if (l == 0) red[w] = s;
  __syncthreads();
  float mean = (red[0] + red[1] + red[2] + red[3]) * (1.f / 1024.f);
  float d0 = x0 - mean, d1 = x1 - mean, d2 = x2 - mean, d3 = x3 - mean;
  float v = d0 * d0 + d1 * d1 + d2 * d2 + d3 * d3;
#pragma unroll
  for (int m = 1; m < 64; m <<= 1) v += __shfl_xor(v, m, 64);
  if (l == 0) red[4 + w] = v;
  __syncthreads();
  float var = (red[4] + red[5] + red[6] + red[7]) * (1.f / 1024.f);
  float rstd = rsqrtf(var + 1e-5f);
  float4 gv = *(const float4*)(g + t * 4);
  float4 bv = *(const float4*)(bb + t * 4);
  float4 o;
  o.x = d0 * rstd * gv.x + bv.x;
  o.y = d1 * rstd * gv.y + bv.y;
  o.z = d2 * rstd * gv.z + bv.z;
  o.w = d3 * rstd * gv.w + bv.w;
  *(float4*)(out + (size_t)row * 1024 + t * 4) = o;
}

extern "C" void kernel_launch(void* const* d_in, const int* in_sizes, int n_in,
                              void* d_out, int out_size, void* d_ws, size_t ws_size,
                              hipStream_t stream) {
  const float* query = (const float*)d_in[0];
  const float* key_  = (const float*)d_in[1];
  const float* value = (const float*)d_in[2];
  const float* wq = (const float*)d_in[3];
  const float* bq = (const float*)d_in[4];
  const float* wk = (const float*)d_in[5];
  const float* bk = (const float*)d_in[6];
  const float* wv = (const float*)d_in[7];
  const float* bv = (const float*)d_in[8];
  const float* wo = (const float*)d_in[9];
  const float* bo = (const float*)d_in[10];
  const float* w1 = (const float*)d_in[11];
  const float* b1 = (const float*)d_in[12];
  const float* w2 = (const float*)d_in[13];
  const float* b2 = (const float*)d_in[14];
  const float* lam = (const float*)d_in[15];
  const float* lng = (const float*)d_in[16];
  const float* lnb = (const float*)d_in[17];

  char* ws = (char*)d_ws;
  size_t off = 0;
  auto alloc = [&](size_t n) { char* p = ws + off; off += (n + 255) & ~(size_t)255; return p; };
  unsigned short* qb  = (unsigned short*)alloc(8388608);   // query bf16 [4096,1024]
  unsigned short* kb  = (unsigned short*)alloc(8388608);
  unsigned short* vb  = (unsigned short*)alloc(8388608);
  unsigned short* wqb = (unsigned short*)alloc(2097152);
  unsigned short* wkb = (unsigned short*)alloc(2097152);
  unsigned short* wvb = (unsigned short*)alloc(2097152);
  unsigned short* wob = (unsigned short*)alloc(2097152);
  unsigned short* w1b = (unsigned short*)alloc(1048576);
  unsigned short* Qp  = (unsigned short*)alloc(8388608);   // projected Q (pre-scaled) bf16
  unsigned short* Kp  = (unsigned short*)alloc(8388608);
  unsigned short* Vt  = (unsigned short*)alloc(8388608);   // V^T bf16 [1024 d_model][4096 tokens]
  unsigned short* h1q = (unsigned short*)alloc(4194304);   // gelu(x@w1^T) bf16 [4096,512]
  unsigned short* h1k = (unsigned short*)alloc(4194304);
  float* vadq = (float*)alloc(49152);                      // [4096,3]
  float* vadk = (float*)alloc(49152);
  unsigned short* Obuf = (unsigned short*)alloc(8388608);  // attention out bf16
  // aliases (stream-ordered lifetimes):
  unsigned short* aff = vb;          // [4][1024 q][1024 k] bf16 (vb dead after proj_k)
  float* tmpA = (float*)qb;          // fp32 [4096,1024] over qb+kb (dead after proj_k)
  float* tmpB = (float*)Qp;          // fp32 [4096,1024] over Qp+Kp (dead after attn_k)

  cvt3_k<<<dim3(2048, 3), 256, 0, stream>>>(query, key_, value, qb, kb, vb, 4194304);
  cvt5_k<<<dim3(512, 5), 256, 0, stream>>>(wq, wk, wv, wo, w1, wqb, wkb, wvb, wob, w1b);

  // all five projection GEMMs in ONE 1024-block launch (4 blocks/CU)
  proj_k<<<1024, 256, 0, stream>>>(qb, kb, vb, wqb, wkb, wvb, w1b,
                                   bq, bk, bv, b1, Qp, Kp, Vt, h1q, h1k);
  vad2_k<<<dim3(1024, 2), 256, 0, stream>>>(h1q, h1k, w2, b2, vadq, vadk);
  aff_k<<<dim3(16, 16, 4), 256, 0, stream>>>(vadq, vadk, lam, aff);
  attn_k<<<dim3(16, 16, 4), 256, 0, stream>>>(Qp, Kp, Vt, aff, Obuf);
  wo_k<<<512, 256, 0, stream>>>(Obuf, wob, bo, tmpA, tmpB);
  ln_k<<<4096, 256, 0, stream>>>(query, tmpA, tmpB, lng, lnb, (float*)d_out);
}